// Round 12
// baseline (655.228 us; speedup 1.0000x reference)
//
#include <hip/hip_runtime.h>
#include <math.h>

#define LSEQ 2048
#define NB   32
#define DM   256
#define RT   65536   // total rows B*L
#define LDT  80      // P-transpose LDS row stride (shorts)

// XOR slot swizzle: 8-elem block q of row c stored at slot SW8(c,q) (involution)
#define SW8(c, q) (((q) & 8) | (((q) ^ (c)) & 7))

typedef float f4 __attribute__((ext_vector_type(4)));
typedef __attribute__((ext_vector_type(4))) float f32x4;
typedef __attribute__((ext_vector_type(8))) short bf16x8;

#define MFMA16 __builtin_amdgcn_mfma_f32_16x16x32_bf16

// ---- bf16 helpers (bit-level, RNE) ----------------------------------------

__device__ __forceinline__ short f2bf(float f) {
  unsigned u = __float_as_uint(f);
  unsigned r = (u + 0x7fffu + ((u >> 16) & 1u)) >> 16;
  return (short)r;
}
__device__ __forceinline__ float bf2f(short s) {
  return __uint_as_float(((unsigned)(unsigned short)s) << 16);
}
__device__ __forceinline__ float tanh_fast(float z) {
  float e = __expf(2.f * z);
  return 1.f - __fdividef(2.f, 1.f + e);
}

// ---- x -> split bf16 + text_mean partial (fused, x read once) -------------

__global__ __launch_bounds__(256) void cvt_x_tm(const float* __restrict__ x,
                                                short* __restrict__ xh,
                                                short* __restrict__ xl,
                                                float* __restrict__ tp) {
  int lc = blockIdx.x, b = blockIdx.y, d = threadIdx.x;
  long rbase = (long)b * LSEQ + lc * 128;
  const float* xp = x + rbase * DM + d;
  short* xhp = xh + rbase * DM + d;
  short* xlp = xl + rbase * DM + d;
  float a = 0.f;
#pragma unroll 4
  for (int i = 0; i < 128; ++i) {
    float v = xp[(long)i * DM];
    a += v;
    short hh = f2bf(v);
    xhp[(long)i * DM] = hh;
    xlp[(long)i * DM] = f2bf(v - bf2f(hh));
  }
  tp[((long)lc * NB + b) * DM + d] = a;
}

__global__ __launch_bounds__(256) void tm_reduce_k(const float* __restrict__ tp,
                                                   float* __restrict__ tm) {
  int idx = blockIdx.x * 256 + threadIdx.x;   // < 8192
  int b = idx >> 8, d = idx & 255;
  float a = 0.f;
#pragma unroll
  for (int lc = 0; lc < 16; ++lc) a += tp[((long)lc * NB + b) * DM + d];
  tm[idx] = a * (1.f / LSEQ);
}

// ---- weight conversions to split-bf16 -------------------------------------

__global__ __launch_bounds__(256) void cvt_ce(const float* __restrict__ ce,
                                              short* __restrict__ h,
                                              short* __restrict__ l, int C) {
  int idx = blockIdx.x * 256 + threadIdx.x;   // < 131072, [c][128k]
  int c = idx >> 7, k = idx & 127;
  float v = (c < C && k < 100) ? ce[c * 100 + k] : 0.f;
  short hh = f2bf(v);
  h[idx] = hh;
  l[idx] = f2bf(v - bf2f(hh));
}

__global__ __launch_bounds__(256) void cvt_aw(const float* __restrict__ aw,
                                              short* __restrict__ h,
                                              short* __restrict__ l) {
  int idx = blockIdx.x * 256 + threadIdx.x;   // < 32768, [e][256k]
  int e = idx >> 8, k = idx & 255;
  float v = (e < 100) ? aw[k * 100 + e] : 0.f;
  short hh = f2bf(v);
  h[idx] = hh;
  l[idx] = f2bf(v - bf2f(hh));
}

// ---- s_mfma: sG[r][e] = split_bf16(tanh(prev[r]*(x@aw)[r][e])) ------------
// grid (1024): 64-row blocks, 4 waves x 16 rows. x half-tile staged in LDS
// once per kh (x read ONCE); both 64-e strips computed inside the block.
// acc[2][4]=32 VGPR -> no spill.

__global__ __launch_bounds__(256) void s_mfma(const short* __restrict__ xh,
                                              const short* __restrict__ xl,
                                              const short* __restrict__ awh,
                                              const short* __restrict__ awl,
                                              const float* __restrict__ prevb,
                                              short* __restrict__ sGh,
                                              short* __restrict__ sGl, int hasPrev) {
  __shared__ __align__(16) short xsh[8192];   // 64 r x 128 k (half), swizzled
  __shared__ __align__(16) short xsl[8192];
  __shared__ __align__(16) short bwh[8192];   // 64 e x 128 k (half), swizzled
  __shared__ __align__(16) short bwl[8192];
  const int tid = threadIdx.x, lane = tid & 63, wv = tid >> 6;
  const int lo = lane & 15, hi = lane >> 4;
  const long r0b = (long)blockIdx.x * 64;
  const long r0 = r0b + wv * 16;

  float pv[4];
#pragma unroll
  for (int q = 0; q < 4; ++q)
    pv[q] = hasPrev ? prevb[r0 + hi * 4 + q] : 1.f;

  f32x4 acc[2][4];   // [strip][n]
#pragma unroll
  for (int st = 0; st < 2; ++st)
#pragma unroll
    for (int n = 0; n < 4; ++n) acc[st][n] = (f32x4){0.f, 0.f, 0.f, 0.f};

#pragma unroll 1
  for (int kh = 0; kh < 2; ++kh) {
    __syncthreads();   // prior compute's LDS reads done
    // stage x half-tile (64 rows x 128 k), swizzled
#pragma unroll
    for (int j = 0; j < 4; ++j) {
      int slot = tid + j * 256;
      int row = slot >> 4, q = slot & 15;
      int dst = row * 128 + SW8(row, q) * 8;
      *(bf16x8*)(xsh + dst) = *(const bf16x8*)(xh + (r0b + row) * 256 + kh * 128 + q * 8);
      *(bf16x8*)(xsl + dst) = *(const bf16x8*)(xl + (r0b + row) * 256 + kh * 128 + q * 8);
    }
    // stage aw strip 0 (64 e x 128 k of half kh), swizzled
#pragma unroll
    for (int j = 0; j < 4; ++j) {
      int slot = tid + j * 256;
      int c = slot >> 4, q = slot & 15;
      int dst = c * 128 + SW8(c, q) * 8;
      *(bf16x8*)(bwh + dst) = *(const bf16x8*)(awh + (long)c * 256 + kh * 128 + q * 8);
      *(bf16x8*)(bwl + dst) = *(const bf16x8*)(awl + (long)c * 256 + kh * 128 + q * 8);
    }
    __syncthreads();

#pragma unroll 1
    for (int st = 0; st < 2; ++st) {
      if (st == 1) {
        __syncthreads();   // strip-0 B reads done
#pragma unroll
        for (int j = 0; j < 4; ++j) {
          int slot = tid + j * 256;
          int c = slot >> 4, q = slot & 15;
          int dst = c * 128 + SW8(c, q) * 8;
          *(bf16x8*)(bwh + dst) =
              *(const bf16x8*)(awh + (long)(64 + c) * 256 + kh * 128 + q * 8);
          *(bf16x8*)(bwl + dst) =
              *(const bf16x8*)(awl + (long)(64 + c) * 256 + kh * 128 + q * 8);
        }
        __syncthreads();
      }
      const int rl = wv * 16 + lo;
#pragma unroll
      for (int ks = 0; ks < 4; ++ks) {
        int xidx = rl * 128 + SW8(rl, ks * 4 + hi) * 8;
        bf16x8 Axh = *(const bf16x8*)(xsh + xidx);
        bf16x8 Axl = *(const bf16x8*)(xsl + xidx);
        bf16x8 Bh[4], Bl[4];
#pragma unroll
        for (int n = 0; n < 4; ++n) {
          int c = n * 16 + lo;
          int idx = c * 128 + SW8(c, ks * 4 + hi) * 8;
          Bh[n] = *(const bf16x8*)(bwh + idx);
          Bl[n] = *(const bf16x8*)(bwl + idx);
        }
#pragma unroll
        for (int n = 0; n < 4; ++n) {
          acc[st][n] = MFMA16(Axh, Bh[n], acc[st][n], 0, 0, 0);
          acc[st][n] = MFMA16(Axl, Bh[n], acc[st][n], 0, 0, 0);
          acc[st][n] = MFMA16(Axh, Bl[n], acc[st][n], 0, 0, 0);
        }
      }
    }
  }

#pragma unroll
  for (int st = 0; st < 2; ++st)
#pragma unroll
    for (int n = 0; n < 4; ++n)
#pragma unroll
      for (int q = 0; q < 4; ++q) {
        long r = r0 + hi * 4 + q;
        int c = st * 64 + n * 16 + lo;
        float t = tanh_fast(pv[q] * acc[st][n][q]);
        short hh = f2bf(t);
        sGh[r * 128 + c] = hh;
        sGl[r * 128 + c] = f2bf(t - bf2f(hh));
      }
}

// ---- A-fragment load (resident) -------------------------------------------

__device__ __forceinline__ void load_afrags(const short* __restrict__ sGh,
                                            const short* __restrict__ sGl,
                                            long r0, int lo, int hi,
                                            bf16x8 (&Ah)[2][4], bf16x8 (&Al)[2][4]) {
#pragma unroll
  for (int m = 0; m < 2; ++m)
#pragma unroll
    for (int ks = 0; ks < 4; ++ks) {
      long off = (r0 + m * 16 + lo) * 128 + ks * 32 + hi * 8;
      Ah[m][ks] = *(const bf16x8*)(sGh + off);
      Al[m][ks] = *(const bf16x8*)(sGl + off);
    }
}

// ---- mfma_colP: LDS-staged ce GEMM + col partials + P=exp bf16 ------------
// grid (512, SG); transpose-LDS aliased over staging buffers (32KB total)

__global__ __launch_bounds__(256) void mfma_colP(const short* __restrict__ sGh,
                                                 const short* __restrict__ sGl,
                                                 const short* __restrict__ ceh,
                                                 const short* __restrict__ cel,
                                                 float* __restrict__ partial,
                                                 short* __restrict__ P,
                                                 int cpb, int CP) {
  __shared__ __align__(16) short smem[16384];   // bufh | bufl, tlds aliased
  short* bufh = smem;
  short* bufl = smem + 8192;
  const int tid = threadIdx.x, lane = tid & 63, wv = tid >> 6;
  const int lo = lane & 15, hi = lane >> 4;
  const long r0 = (long)blockIdx.x * 128 + wv * 32;
  const long gw = (long)blockIdx.x * 4 + wv;
  const int s0 = blockIdx.y * cpb;
  const int oct = lane & 7;
  short* tw = smem + wv * (32 * LDT);   // per-wave transpose region (aliased)

  bf16x8 Ah[2][4], Al[2][4];
  load_afrags(sGh, sGl, r0, lo, hi, Ah, Al);

#pragma unroll 1
  for (int s = 0; s < cpb; ++s) {
    const int c0s = (s0 + s) * 64;
    __syncthreads();   // prior epilogue (tlds) done -> buf reusable
    {  // stage ce strip (64 cols x 128 k), hi + lo, swizzled
      const short* gh = ceh + (long)c0s * 128;
      const short* gl = cel + (long)c0s * 128;
#pragma unroll
      for (int j = 0; j < 4; ++j) {
        int slot = tid + j * 256;
        int c = slot >> 4, q = slot & 15;
        int dst = c * 128 + SW8(c, q) * 8;
        *(bf16x8*)(bufh + dst) = *(const bf16x8*)(gh + slot * 8);
        *(bf16x8*)(bufl + dst) = *(const bf16x8*)(gl + slot * 8);
      }
    }
    __syncthreads();   // buf ready

    f32x4 acc[2][4];
#pragma unroll
    for (int m = 0; m < 2; ++m)
#pragma unroll
      for (int n = 0; n < 4; ++n) acc[m][n] = (f32x4){0.f, 0.f, 0.f, 0.f};

#pragma unroll
    for (int ks = 0; ks < 4; ++ks) {
      bf16x8 Bh[4], Bl[4];
#pragma unroll
      for (int n = 0; n < 4; ++n) {
        int c = n * 16 + lo;
        int idx = c * 128 + SW8(c, ks * 4 + hi) * 8;
        Bh[n] = *(const bf16x8*)(bufh + idx);
        Bl[n] = *(const bf16x8*)(bufl + idx);
      }
#pragma unroll
      for (int n = 0; n < 4; ++n) {
        acc[0][n] = MFMA16(Ah[0][ks], Bh[n], acc[0][n], 0, 0, 0);
        acc[1][n] = MFMA16(Ah[1][ks], Bh[n], acc[1][n], 0, 0, 0);
        acc[0][n] = MFMA16(Al[0][ks], Bh[n], acc[0][n], 0, 0, 0);
        acc[1][n] = MFMA16(Al[1][ks], Bh[n], acc[1][n], 0, 0, 0);
        acc[0][n] = MFMA16(Ah[0][ks], Bl[n], acc[0][n], 0, 0, 0);
        acc[1][n] = MFMA16(Ah[1][ks], Bl[n], acc[1][n], 0, 0, 0);
      }
    }
    __syncthreads();   // all B-frag reads done -> buf dead, tlds may overwrite

    // epilogue: exp -> col partial + per-wave LDS transpose for P stores
#pragma unroll
    for (int n = 0; n < 4; ++n) {
      float sum = 0.f;
#pragma unroll
      for (int m = 0; m < 2; ++m)
#pragma unroll
        for (int q = 0; q < 4; ++q) {
          float e = __expf(acc[m][n][q]);
          sum += e;
          tw[(m * 16 + hi * 4 + q) * LDT + n * 16 + lo] = f2bf(e);
        }
      sum += __shfl_xor(sum, 16);
      sum += __shfl_xor(sum, 32);
      if (lane < 16) partial[gw * 1024 + c0s + n * 16 + lane] = sum;
    }
#pragma unroll
    for (int j = 0; j < 4; ++j) {
      int rl = (lane >> 3) + j * 8;
      bf16x8 v = *(const bf16x8*)(&tw[rl * LDT + oct * 8]);
      *(bf16x8*)(P + (r0 + rl) * (long)CP + c0s + oct * 8) = v;
    }
  }
}

// ---- wz: Z = sum of 64 wave partials per batch; w = 1/(C*Z) ---------------

__global__ __launch_bounds__(256) void wz_kernel(const float* __restrict__ partial,
                                                 float* __restrict__ Z,
                                                 float* __restrict__ w, int C) {
  int idx = blockIdx.x * 256 + threadIdx.x;  // < 32768
  int b = idx >> 10, c = idx & 1023;
  float z = 0.f;
#pragma unroll 8
  for (int i = 0; i < 64; ++i) z += partial[(long)(b * 64 + i) * 1024 + c];
  Z[idx] = z;
  w[idx] = (c < C) ? 1.f / ((float)C * z) : 0.f;
}

// ---- rowpass: out[r] = (ps[r]?) * sum_c P[r][c]*w[c]  (wave per row) ------

__global__ __launch_bounds__(256) void rowpass_k(const short* __restrict__ P,
                                                 const float* __restrict__ w,
                                                 const float* __restrict__ ps,
                                                 float* __restrict__ out, int CP) {
  const int lane = threadIdx.x & 63, wv = threadIdx.x >> 6;
  const long r = (long)blockIdx.x * 4 + wv;
  const int b = (int)(r >> 11);
  const short* Pr = P + r * (long)CP;
  const float* wb_ = w + b * 1024;
  float acc = 0.f;
  for (int c0 = lane * 8; c0 < CP; c0 += 512) {
    bf16x8 pv = *(const bf16x8*)(Pr + c0);
    f4 w0 = *(const f4*)(wb_ + c0);
    f4 w1 = *(const f4*)(wb_ + c0 + 4);
    acc = fmaf(bf2f(pv[0]), w0[0], acc);
    acc = fmaf(bf2f(pv[1]), w0[1], acc);
    acc = fmaf(bf2f(pv[2]), w0[2], acc);
    acc = fmaf(bf2f(pv[3]), w0[3], acc);
    acc = fmaf(bf2f(pv[4]), w1[0], acc);
    acc = fmaf(bf2f(pv[5]), w1[1], acc);
    acc = fmaf(bf2f(pv[6]), w1[2], acc);
    acc = fmaf(bf2f(pv[7]), w1[3], acc);
  }
  acc += __shfl_xor(acc, 1);
  acc += __shfl_xor(acc, 2);
  acc += __shfl_xor(acc, 4);
  acc += __shfl_xor(acc, 8);
  acc += __shfl_xor(acc, 16);
  acc += __shfl_xor(acc, 32);
  if (lane == 0) out[r] = ps ? acc * ps[r] : acc;
}

// ---- pooled = sum_l gs[b,l]*x[b,l,:]  (coalesced ushort2 reads) -----------

__global__ __launch_bounds__(256) void pooled_partial_k(const short* __restrict__ xh,
                                                        const float* __restrict__ gs,
                                                        float* __restrict__ pp) {
  int lc = blockIdx.x, b = blockIdx.y;
  int rr = threadIdx.x >> 7, dd = threadIdx.x & 127;
  long rbase = (long)b * LSEQ + lc * 256 + rr * 128;
  const short* xp = xh + rbase * DM + dd * 2;
  const float* gp = gs + rbase;
  float a0 = 0.f, a1 = 0.f;
#pragma unroll 4
  for (int i = 0; i < 128; ++i) {
    unsigned v = *(const unsigned*)(xp + (long)i * DM);
    float g = gp[i];
    a0 = fmaf(g, __uint_as_float((v & 0xffffu) << 16), a0);
    a1 = fmaf(g, __uint_as_float(v & 0xffff0000u), a1);
  }
  float* dst = pp + ((long)(lc * 2 + rr) * NB + b) * DM + dd * 2;
  dst[0] = a0;
  dst[1] = a1;
}

// ---- pooled reduce + dense = relu([tm, pooled] @ dw + db) (fused) ---------

__global__ __launch_bounds__(256) void pooled_dense_k(const float* __restrict__ pp,
                                                      const float* __restrict__ tm,
                                                      const float* __restrict__ dw,
                                                      const float* __restrict__ db,
                                                      float* __restrict__ dense) {
  __shared__ float f[2 * DM];
  int b = blockIdx.x, t = threadIdx.x;
  float a = 0.f;
#pragma unroll
  for (int lc = 0; lc < 16; ++lc) a += pp[((long)lc * NB + b) * DM + t];
  f[DM + t] = a;
  f[t] = tm[b * DM + t];
  __syncthreads();
  float acc = db[t];
#pragma unroll 8
  for (int k = 0; k < 2 * DM; ++k) acc = fmaf(f[k], dw[(long)k * DM + t], acc);
  dense[b * DM + t] = fmaxf(acc, 0.f);
}

// ---- pred: logits + softmax + optional w3 = pred/(C*Z) (fused) ------------

__global__ __launch_bounds__(256) void pred_k(const float* __restrict__ dense,
                                              const float* __restrict__ pw,
                                              const float* __restrict__ pb,
                                              const float* __restrict__ Z,
                                              float* __restrict__ out,
                                              float* __restrict__ w,
                                              int C, int writeW) {
  __shared__ float dS[DM];
  __shared__ float buf[1024];
  __shared__ float red[256];
  int b = blockIdx.x, t = threadIdx.x;
  dS[t] = dense[b * DM + t];
  __syncthreads();
  float m = -1e30f;
  for (int c = t; c < C; c += 256) {
    float a = pb[c];
#pragma unroll 8
    for (int k = 0; k < DM; ++k) a = fmaf(dS[k], pw[(long)k * C + c], a);
    buf[c] = a;
    m = fmaxf(m, a);
  }
  red[t] = m;
  __syncthreads();
  for (int s2 = 128; s2 > 0; s2 >>= 1) {
    if (t < s2) red[t] = fmaxf(red[t], red[t + s2]);
    __syncthreads();
  }
  m = red[0];
  __syncthreads();
  float sum = 0.f;
  for (int c = t; c < C; c += 256) {
    float e = __expf(buf[c] - m);
    buf[c] = e;
    sum += e;
  }
  red[t] = sum;
  __syncthreads();
  for (int s2 = 128; s2 > 0; s2 >>= 1) {
    if (t < s2) red[t] += red[t + s2];
    __syncthreads();
  }
  float inv = 1.f / red[0];
  for (int c = t; c < C; c += 256) out[(long)b * C + c] = buf[c] * inv;
  if (writeW) {
    float invC = 1.f / (float)C;
    for (int c = t; c < 1024; c += 256)
      w[b * 1024 + c] = (c < C) ? (buf[c] * inv) * invC / Z[b * 1024 + c] : 0.f;
  }
}

// ---- host -----------------------------------------------------------------

extern "C" void kernel_launch(void* const* d_in, const int* in_sizes, int n_in,
                              void* d_out, int out_size, void* d_ws, size_t ws_size,
                              hipStream_t stream) {
  (void)in_sizes; (void)n_in; (void)out_size; (void)ws_size;
  const float* x = (const float*)d_in[0];

  const int Cs[3]     = {21, 191, 1009};
  const int CPs[3]    = {64, 192, 1024};  // padded P row length
  const int SGs[3]    = {1, 1, 2};        // strip-groups (grid.y)
  const int CPBs[3]   = {1, 3, 8};        // strips per block; SG*CPB*64 == CP
  const int outoff[3] = {0, 672, 6784};

  char* base = (char*)d_ws;
  short* xh  = (short*)base; base += (size_t)RT * 256 * 2;
  short* xl  = (short*)base; base += (size_t)RT * 256 * 2;
  short* sGh = (short*)base; base += (size_t)RT * 128 * 2;
  short* sGl = (short*)base; base += (size_t)RT * 128 * 2;
  short* Pb  = (short*)base; base += (size_t)RT * 1024 * 2;   // P bf16
  short* ceh = (short*)base; base += (size_t)3 * 131072 * 2;
  short* cel = (short*)base; base += (size_t)3 * 131072 * 2;
  short* awh = (short*)base; base += (size_t)3 * 32768 * 2;
  short* awl = (short*)base; base += (size_t)3 * 32768 * 2;
  float* partial = (float*)base; base += (size_t)2048 * 1024 * 4;
  float* Zb     = (float*)base; base += 32768 * 4;
  float* wb     = (float*)base; base += 32768 * 4;
  float* gs     = (float*)base; base += RT * 4;
  float* prevb  = (float*)base; base += RT * 4;
  float* tp     = (float*)base; base += 131072 * 4;
  float* tm     = (float*)base; base += 8192 * 4;
  float* pp     = (float*)base; base += 131072 * 4;
  float* dense  = (float*)base; base += 8192 * 4;

  cvt_x_tm<<<dim3(16, NB), 256, 0, stream>>>(x, xh, xl, tp);
  tm_reduce_k<<<32, 256, 0, stream>>>(tp, tm);
  for (int h = 0; h < 3; ++h) {
    cvt_ce<<<512, 256, 0, stream>>>((const float*)d_in[1 + 6 * h], ceh + h * 131072,
                                    cel + h * 131072, Cs[h]);
    cvt_aw<<<128, 256, 0, stream>>>((const float*)d_in[1 + 6 * h + 1], awh + h * 32768,
                                    awl + h * 32768);
  }

  for (int h = 0; h < 3; ++h) {
    const float* dw = (const float*)d_in[1 + 6 * h + 2];
    const float* db = (const float*)d_in[1 + 6 * h + 3];
    const float* pw = (const float*)d_in[1 + 6 * h + 4];
    const float* pb = (const float*)d_in[1 + 6 * h + 5];
    const short* ch = ceh + h * 131072;
    const short* cl = cel + h * 131072;
    const int C = Cs[h], CP = CPs[h], SG = SGs[h], CPB = CPBs[h];

    s_mfma<<<1024, 256, 0, stream>>>(xh, xl, awh + h * 32768, awl + h * 32768,
                                     prevb, sGh, sGl, h > 0 ? 1 : 0);
    mfma_colP<<<dim3(512, SG), 256, 0, stream>>>(sGh, sGl, ch, cl, partial, Pb, CPB, CP);
    wz_kernel<<<128, 256, 0, stream>>>(partial, Zb, wb, C);
    rowpass_k<<<RT / 4, 256, 0, stream>>>(Pb, wb, h > 0 ? prevb : nullptr, gs, CP);
    pooled_partial_k<<<dim3(8, NB), 256, 0, stream>>>(xh, gs, pp);
    pooled_dense_k<<<NB, 256, 0, stream>>>(pp, tm, dw, db, dense);
    pred_k<<<NB, 256, 0, stream>>>(dense, pw, pb, Zb, (float*)d_out + outoff[h], wb, C,
                                   h < 2 ? 1 : 0);
    if (h < 2)
      rowpass_k<<<RT / 4, 256, 0, stream>>>(Pb, wb, nullptr, prevb, CP);
  }
}

// Round 13
// 551.778 us; speedup vs baseline: 1.1875x; 1.1875x over previous
//
#include <hip/hip_runtime.h>
#include <math.h>

#define LSEQ 2048
#define NB   32
#define DM   256
#define RT   65536   // total rows B*L
#define LDT  80      // P-transpose LDS row stride (shorts)

// XOR slot swizzle: 8-elem block q of row c stored at slot SW8(c,q) (involution)
#define SW8(c, q) (((q) & 8) | (((q) ^ (c)) & 7))

typedef float f4 __attribute__((ext_vector_type(4)));
typedef __attribute__((ext_vector_type(4))) float f32x4;
typedef __attribute__((ext_vector_type(8))) short bf16x8;

#define MFMA16 __builtin_amdgcn_mfma_f32_16x16x32_bf16

// ---- bf16 helpers (bit-level, RNE) ----------------------------------------

__device__ __forceinline__ short f2bf(float f) {
  unsigned u = __float_as_uint(f);
  unsigned r = (u + 0x7fffu + ((u >> 16) & 1u)) >> 16;
  return (short)r;
}
__device__ __forceinline__ float bf2f(short s) {
  return __uint_as_float(((unsigned)(unsigned short)s) << 16);
}
__device__ __forceinline__ float tanh_fast(float z) {
  float e = __expf(2.f * z);
  return 1.f - __fdividef(2.f, 1.f + e);
}

// ---- x -> split bf16 + text_mean partial (fused, x read once) -------------

__global__ __launch_bounds__(256) void cvt_x_tm(const float* __restrict__ x,
                                                short* __restrict__ xh,
                                                short* __restrict__ xl,
                                                float* __restrict__ tp) {
  int lc = blockIdx.x, b = blockIdx.y, d = threadIdx.x;
  long rbase = (long)b * LSEQ + lc * 128;
  const float* xp = x + rbase * DM + d;
  short* xhp = xh + rbase * DM + d;
  short* xlp = xl + rbase * DM + d;
  float a = 0.f;
#pragma unroll 4
  for (int i = 0; i < 128; ++i) {
    float v = xp[(long)i * DM];
    a += v;
    short hh = f2bf(v);
    xhp[(long)i * DM] = hh;
    xlp[(long)i * DM] = f2bf(v - bf2f(hh));
  }
  tp[((long)lc * NB + b) * DM + d] = a;
}

__global__ __launch_bounds__(256) void tm_reduce_k(const float* __restrict__ tp,
                                                   float* __restrict__ tm) {
  int idx = blockIdx.x * 256 + threadIdx.x;   // < 8192
  int b = idx >> 8, d = idx & 255;
  float a = 0.f;
#pragma unroll
  for (int lc = 0; lc < 16; ++lc) a += tp[((long)lc * NB + b) * DM + d];
  tm[idx] = a * (1.f / LSEQ);
}

// ---- weight conversions to split-bf16 -------------------------------------

__global__ __launch_bounds__(256) void cvt_ce(const float* __restrict__ ce,
                                              short* __restrict__ h,
                                              short* __restrict__ l, int C) {
  int idx = blockIdx.x * 256 + threadIdx.x;   // < 131072, [c][128k]
  int c = idx >> 7, k = idx & 127;
  float v = (c < C && k < 100) ? ce[c * 100 + k] : 0.f;
  short hh = f2bf(v);
  h[idx] = hh;
  l[idx] = f2bf(v - bf2f(hh));
}

__global__ __launch_bounds__(256) void cvt_aw(const float* __restrict__ aw,
                                              short* __restrict__ h,
                                              short* __restrict__ l) {
  int idx = blockIdx.x * 256 + threadIdx.x;   // < 32768, [e][256k]
  int e = idx >> 8, k = idx & 255;
  float v = (e < 100) ? aw[k * 100 + e] : 0.f;
  short hh = f2bf(v);
  h[idx] = hh;
  l[idx] = f2bf(v - bf2f(hh));
}

// ---- s_mfma (R10 version): grid (512,2); 4 waves x 32 rows; ONE 64-e strip
// per block; aw staged in LDS per k-half. acc[2][4]=32 regs -> no spill.

__global__ __launch_bounds__(256) void s_mfma(const short* __restrict__ xh,
                                              const short* __restrict__ xl,
                                              const short* __restrict__ awh,
                                              const short* __restrict__ awl,
                                              const float* __restrict__ prevb,
                                              short* __restrict__ sGh,
                                              short* __restrict__ sGl, int hasPrev) {
  __shared__ __align__(16) short bufh[8192];   // 64 e x 128 k, swizzled slots
  __shared__ __align__(16) short bufl[8192];
  const int tid = threadIdx.x, lane = tid & 63, wv = tid >> 6;
  const int lo = lane & 15, hi = lane >> 4;
  const int st = blockIdx.y;
  const long r0 = (long)blockIdx.x * 128 + wv * 32;

  float pv[2][4];
#pragma unroll
  for (int m = 0; m < 2; ++m)
#pragma unroll
    for (int q = 0; q < 4; ++q)
      pv[m][q] = hasPrev ? prevb[r0 + m * 16 + hi * 4 + q] : 1.f;

  f32x4 acc[2][4];
#pragma unroll
  for (int m = 0; m < 2; ++m)
#pragma unroll
    for (int n = 0; n < 4; ++n) acc[m][n] = (f32x4){0.f, 0.f, 0.f, 0.f};

#pragma unroll 1
  for (int kh = 0; kh < 2; ++kh) {
    __syncthreads();
    {  // stage aw strip rows e=0..63 of half kh (16KB hi + 16KB lo), swizzled
      const short* gh = awh + (long)st * 64 * 256 + kh * 128;
      const short* gl = awl + (long)st * 64 * 256 + kh * 128;
#pragma unroll
      for (int j = 0; j < 4; ++j) {
        int slot = tid + j * 256;
        int c = slot >> 4, q = slot & 15;
        int dst = c * 128 + SW8(c, q) * 8;
        *(bf16x8*)(bufh + dst) = *(const bf16x8*)(gh + (long)c * 256 + q * 8);
        *(bf16x8*)(bufl + dst) = *(const bf16x8*)(gl + (long)c * 256 + q * 8);
      }
    }
    // A fragments for this k-half (global, coalesced 16B/lane)
    bf16x8 Ah[2][4], Al[2][4];
#pragma unroll
    for (int m = 0; m < 2; ++m)
#pragma unroll
      for (int ks = 0; ks < 4; ++ks) {
        long off = (r0 + m * 16 + lo) * 256 + kh * 128 + ks * 32 + hi * 8;
        Ah[m][ks] = *(const bf16x8*)(xh + off);
        Al[m][ks] = *(const bf16x8*)(xl + off);
      }
    __syncthreads();
#pragma unroll
    for (int ks = 0; ks < 4; ++ks) {
      bf16x8 Bh[4], Bl[4];
#pragma unroll
      for (int n = 0; n < 4; ++n) {
        int c = n * 16 + lo;
        int idx = c * 128 + SW8(c, ks * 4 + hi) * 8;
        Bh[n] = *(const bf16x8*)(bufh + idx);
        Bl[n] = *(const bf16x8*)(bufl + idx);
      }
#pragma unroll
      for (int n = 0; n < 4; ++n) {
        acc[0][n] = MFMA16(Ah[0][ks], Bh[n], acc[0][n], 0, 0, 0);
        acc[1][n] = MFMA16(Ah[1][ks], Bh[n], acc[1][n], 0, 0, 0);
        acc[0][n] = MFMA16(Al[0][ks], Bh[n], acc[0][n], 0, 0, 0);
        acc[1][n] = MFMA16(Al[1][ks], Bh[n], acc[1][n], 0, 0, 0);
        acc[0][n] = MFMA16(Ah[0][ks], Bl[n], acc[0][n], 0, 0, 0);
        acc[1][n] = MFMA16(Ah[1][ks], Bl[n], acc[1][n], 0, 0, 0);
      }
    }
  }

#pragma unroll
  for (int m = 0; m < 2; ++m)
#pragma unroll
    for (int n = 0; n < 4; ++n)
#pragma unroll
      for (int q = 0; q < 4; ++q) {
        long r = r0 + m * 16 + hi * 4 + q;
        int c = st * 64 + n * 16 + lo;
        float t = tanh_fast(pv[m][q] * acc[m][n][q]);
        short hh = f2bf(t);
        sGh[r * 128 + c] = hh;
        sGl[r * 128 + c] = f2bf(t - bf2f(hh));
      }
}

// ---- A-fragment load (resident) -------------------------------------------

__device__ __forceinline__ void load_afrags(const short* __restrict__ sGh,
                                            const short* __restrict__ sGl,
                                            long r0, int lo, int hi,
                                            bf16x8 (&Ah)[2][4], bf16x8 (&Al)[2][4]) {
#pragma unroll
  for (int m = 0; m < 2; ++m)
#pragma unroll
    for (int ks = 0; ks < 4; ++ks) {
      long off = (r0 + m * 16 + lo) * 128 + ks * 32 + hi * 8;
      Ah[m][ks] = *(const bf16x8*)(sGh + off);
      Al[m][ks] = *(const bf16x8*)(sGl + off);
    }
}

// ---- mfma_colP: LDS-staged ce GEMM + col partials + P=exp bf16 ------------
// grid (512, SG); transpose-LDS aliased over staging buffers (32KB total)

__global__ __launch_bounds__(256) void mfma_colP(const short* __restrict__ sGh,
                                                 const short* __restrict__ sGl,
                                                 const short* __restrict__ ceh,
                                                 const short* __restrict__ cel,
                                                 float* __restrict__ partial,
                                                 short* __restrict__ P,
                                                 int cpb, int CP) {
  __shared__ __align__(16) short smem[16384];   // bufh | bufl, tlds aliased
  short* bufh = smem;
  short* bufl = smem + 8192;
  const int tid = threadIdx.x, lane = tid & 63, wv = tid >> 6;
  const int lo = lane & 15, hi = lane >> 4;
  const long r0 = (long)blockIdx.x * 128 + wv * 32;
  const long gw = (long)blockIdx.x * 4 + wv;
  const int s0 = blockIdx.y * cpb;
  const int oct = lane & 7;
  short* tw = smem + wv * (32 * LDT);   // per-wave transpose region (aliased)

  bf16x8 Ah[2][4], Al[2][4];
  load_afrags(sGh, sGl, r0, lo, hi, Ah, Al);

#pragma unroll 1
  for (int s = 0; s < cpb; ++s) {
    const int c0s = (s0 + s) * 64;
    __syncthreads();   // prior epilogue (tlds) done -> buf reusable
    {  // stage ce strip (64 cols x 128 k), hi + lo, swizzled
      const short* gh = ceh + (long)c0s * 128;
      const short* gl = cel + (long)c0s * 128;
#pragma unroll
      for (int j = 0; j < 4; ++j) {
        int slot = tid + j * 256;
        int c = slot >> 4, q = slot & 15;
        int dst = c * 128 + SW8(c, q) * 8;
        *(bf16x8*)(bufh + dst) = *(const bf16x8*)(gh + slot * 8);
        *(bf16x8*)(bufl + dst) = *(const bf16x8*)(gl + slot * 8);
      }
    }
    __syncthreads();   // buf ready

    f32x4 acc[2][4];
#pragma unroll
    for (int m = 0; m < 2; ++m)
#pragma unroll
      for (int n = 0; n < 4; ++n) acc[m][n] = (f32x4){0.f, 0.f, 0.f, 0.f};

#pragma unroll
    for (int ks = 0; ks < 4; ++ks) {
      bf16x8 Bh[4], Bl[4];
#pragma unroll
      for (int n = 0; n < 4; ++n) {
        int c = n * 16 + lo;
        int idx = c * 128 + SW8(c, ks * 4 + hi) * 8;
        Bh[n] = *(const bf16x8*)(bufh + idx);
        Bl[n] = *(const bf16x8*)(bufl + idx);
      }
#pragma unroll
      for (int n = 0; n < 4; ++n) {
        acc[0][n] = MFMA16(Ah[0][ks], Bh[n], acc[0][n], 0, 0, 0);
        acc[1][n] = MFMA16(Ah[1][ks], Bh[n], acc[1][n], 0, 0, 0);
        acc[0][n] = MFMA16(Al[0][ks], Bh[n], acc[0][n], 0, 0, 0);
        acc[1][n] = MFMA16(Al[1][ks], Bh[n], acc[1][n], 0, 0, 0);
        acc[0][n] = MFMA16(Ah[0][ks], Bl[n], acc[0][n], 0, 0, 0);
        acc[1][n] = MFMA16(Ah[1][ks], Bl[n], acc[1][n], 0, 0, 0);
      }
    }
    __syncthreads();   // all B-frag reads done -> buf dead, tlds may overwrite

    // epilogue: exp -> col partial + per-wave LDS transpose for P stores
#pragma unroll
    for (int n = 0; n < 4; ++n) {
      float sum = 0.f;
#pragma unroll
      for (int m = 0; m < 2; ++m)
#pragma unroll
        for (int q = 0; q < 4; ++q) {
          float e = __expf(acc[m][n][q]);
          sum += e;
          tw[(m * 16 + hi * 4 + q) * LDT + n * 16 + lo] = f2bf(e);
        }
      sum += __shfl_xor(sum, 16);
      sum += __shfl_xor(sum, 32);
      if (lane < 16) partial[gw * 1024 + c0s + n * 16 + lane] = sum;
    }
#pragma unroll
    for (int j = 0; j < 4; ++j) {
      int rl = (lane >> 3) + j * 8;
      bf16x8 v = *(const bf16x8*)(&tw[rl * LDT + oct * 8]);
      *(bf16x8*)(P + (r0 + rl) * (long)CP + c0s + oct * 8) = v;
    }
  }
}

// ---- wz: Z = sum of 64 wave partials per batch; w = 1/(C*Z) ---------------

__global__ __launch_bounds__(256) void wz_kernel(const float* __restrict__ partial,
                                                 float* __restrict__ Z,
                                                 float* __restrict__ w, int C) {
  int idx = blockIdx.x * 256 + threadIdx.x;  // < 32768
  int b = idx >> 10, c = idx & 1023;
  float z = 0.f;
#pragma unroll 8
  for (int i = 0; i < 64; ++i) z += partial[(long)(b * 64 + i) * 1024 + c];
  Z[idx] = z;
  w[idx] = (c < C) ? 1.f / ((float)C * z) : 0.f;
}

// ---- rowpass: out[r] = (ps[r]?) * sum_c P[r][c]*w[c]  (wave per row) ------

__global__ __launch_bounds__(256) void rowpass_k(const short* __restrict__ P,
                                                 const float* __restrict__ w,
                                                 const float* __restrict__ ps,
                                                 float* __restrict__ out, int CP) {
  const int lane = threadIdx.x & 63, wv = threadIdx.x >> 6;
  const long r = (long)blockIdx.x * 4 + wv;
  const int b = (int)(r >> 11);
  const short* Pr = P + r * (long)CP;
  const float* wb_ = w + b * 1024;
  float acc = 0.f;
  for (int c0 = lane * 8; c0 < CP; c0 += 512) {
    bf16x8 pv = *(const bf16x8*)(Pr + c0);
    f4 w0 = *(const f4*)(wb_ + c0);
    f4 w1 = *(const f4*)(wb_ + c0 + 4);
    acc = fmaf(bf2f(pv[0]), w0[0], acc);
    acc = fmaf(bf2f(pv[1]), w0[1], acc);
    acc = fmaf(bf2f(pv[2]), w0[2], acc);
    acc = fmaf(bf2f(pv[3]), w0[3], acc);
    acc = fmaf(bf2f(pv[4]), w1[0], acc);
    acc = fmaf(bf2f(pv[5]), w1[1], acc);
    acc = fmaf(bf2f(pv[6]), w1[2], acc);
    acc = fmaf(bf2f(pv[7]), w1[3], acc);
  }
  acc += __shfl_xor(acc, 1);
  acc += __shfl_xor(acc, 2);
  acc += __shfl_xor(acc, 4);
  acc += __shfl_xor(acc, 8);
  acc += __shfl_xor(acc, 16);
  acc += __shfl_xor(acc, 32);
  if (lane == 0) out[r] = ps ? acc * ps[r] : acc;
}

// ---- pooled = sum_l gs[b,l]*x[b,l,:]  (coalesced ushort2 reads) -----------

__global__ __launch_bounds__(256) void pooled_partial_k(const short* __restrict__ xh,
                                                        const float* __restrict__ gs,
                                                        float* __restrict__ pp) {
  int lc = blockIdx.x, b = blockIdx.y;
  int rr = threadIdx.x >> 7, dd = threadIdx.x & 127;
  long rbase = (long)b * LSEQ + lc * 256 + rr * 128;
  const short* xp = xh + rbase * DM + dd * 2;
  const float* gp = gs + rbase;
  float a0 = 0.f, a1 = 0.f;
#pragma unroll 4
  for (int i = 0; i < 128; ++i) {
    unsigned v = *(const unsigned*)(xp + (long)i * DM);
    float g = gp[i];
    a0 = fmaf(g, __uint_as_float((v & 0xffffu) << 16), a0);
    a1 = fmaf(g, __uint_as_float(v & 0xffff0000u), a1);
  }
  float* dst = pp + ((long)(lc * 2 + rr) * NB + b) * DM + dd * 2;
  dst[0] = a0;
  dst[1] = a1;
}

// ---- pooled reduce + dense = relu([tm, pooled] @ dw + db) (fused) ---------

__global__ __launch_bounds__(256) void pooled_dense_k(const float* __restrict__ pp,
                                                      const float* __restrict__ tm,
                                                      const float* __restrict__ dw,
                                                      const float* __restrict__ db,
                                                      float* __restrict__ dense) {
  __shared__ float f[2 * DM];
  int b = blockIdx.x, t = threadIdx.x;
  float a = 0.f;
#pragma unroll
  for (int lc = 0; lc < 16; ++lc) a += pp[((long)lc * NB + b) * DM + t];
  f[DM + t] = a;
  f[t] = tm[b * DM + t];
  __syncthreads();
  float acc = db[t];
#pragma unroll 8
  for (int k = 0; k < 2 * DM; ++k) acc = fmaf(f[k], dw[(long)k * DM + t], acc);
  dense[b * DM + t] = fmaxf(acc, 0.f);
}

// ---- pred: logits + softmax + optional w3 = pred/(C*Z) (fused) ------------

__global__ __launch_bounds__(256) void pred_k(const float* __restrict__ dense,
                                              const float* __restrict__ pw,
                                              const float* __restrict__ pb,
                                              const float* __restrict__ Z,
                                              float* __restrict__ out,
                                              float* __restrict__ w,
                                              int C, int writeW) {
  __shared__ float dS[DM];
  __shared__ float buf[1024];
  __shared__ float red[256];
  int b = blockIdx.x, t = threadIdx.x;
  dS[t] = dense[b * DM + t];
  __syncthreads();
  float m = -1e30f;
  for (int c = t; c < C; c += 256) {
    float a = pb[c];
#pragma unroll 8
    for (int k = 0; k < DM; ++k) a = fmaf(dS[k], pw[(long)k * C + c], a);
    buf[c] = a;
    m = fmaxf(m, a);
  }
  red[t] = m;
  __syncthreads();
  for (int s2 = 128; s2 > 0; s2 >>= 1) {
    if (t < s2) red[t] = fmaxf(red[t], red[t + s2]);
    __syncthreads();
  }
  m = red[0];
  __syncthreads();
  float sum = 0.f;
  for (int c = t; c < C; c += 256) {
    float e = __expf(buf[c] - m);
    buf[c] = e;
    sum += e;
  }
  red[t] = sum;
  __syncthreads();
  for (int s2 = 128; s2 > 0; s2 >>= 1) {
    if (t < s2) red[t] += red[t + s2];
    __syncthreads();
  }
  float inv = 1.f / red[0];
  for (int c = t; c < C; c += 256) out[(long)b * C + c] = buf[c] * inv;
  if (writeW) {
    float invC = 1.f / (float)C;
    for (int c = t; c < 1024; c += 256)
      w[b * 1024 + c] = (c < C) ? (buf[c] * inv) * invC / Z[b * 1024 + c] : 0.f;
  }
}

// ---- host -----------------------------------------------------------------

extern "C" void kernel_launch(void* const* d_in, const int* in_sizes, int n_in,
                              void* d_out, int out_size, void* d_ws, size_t ws_size,
                              hipStream_t stream) {
  (void)in_sizes; (void)n_in; (void)out_size; (void)ws_size;
  const float* x = (const float*)d_in[0];

  const int Cs[3]     = {21, 191, 1009};
  const int CPs[3]    = {64, 192, 1024};  // padded P row length
  const int SGs[3]    = {1, 1, 2};        // strip-groups (grid.y)
  const int CPBs[3]   = {1, 3, 8};        // strips per block; SG*CPB*64 == CP
  const int outoff[3] = {0, 672, 6784};

  char* base = (char*)d_ws;
  short* xh  = (short*)base; base += (size_t)RT * 256 * 2;
  short* xl  = (short*)base; base += (size_t)RT * 256 * 2;
  short* sGh = (short*)base; base += (size_t)RT * 128 * 2;
  short* sGl = (short*)base; base += (size_t)RT * 128 * 2;
  short* Pb  = (short*)base; base += (size_t)RT * 1024 * 2;   // P bf16
  short* ceh = (short*)base; base += (size_t)3 * 131072 * 2;
  short* cel = (short*)base; base += (size_t)3 * 131072 * 2;
  short* awh = (short*)base; base += (size_t)3 * 32768 * 2;
  short* awl = (short*)base; base += (size_t)3 * 32768 * 2;
  float* partial = (float*)base; base += (size_t)2048 * 1024 * 4;
  float* Zb     = (float*)base; base += 32768 * 4;
  float* wb     = (float*)base; base += 32768 * 4;
  float* gs     = (float*)base; base += RT * 4;
  float* prevb  = (float*)base; base += RT * 4;
  float* tp     = (float*)base; base += 131072 * 4;
  float* tm     = (float*)base; base += 8192 * 4;
  float* pp     = (float*)base; base += 131072 * 4;
  float* dense  = (float*)base; base += 8192 * 4;

  cvt_x_tm<<<dim3(16, NB), 256, 0, stream>>>(x, xh, xl, tp);
  tm_reduce_k<<<32, 256, 0, stream>>>(tp, tm);
  for (int h = 0; h < 3; ++h) {
    cvt_ce<<<512, 256, 0, stream>>>((const float*)d_in[1 + 6 * h], ceh + h * 131072,
                                    cel + h * 131072, Cs[h]);
    cvt_aw<<<128, 256, 0, stream>>>((const float*)d_in[1 + 6 * h + 1], awh + h * 32768,
                                    awl + h * 32768);
  }

  for (int h = 0; h < 3; ++h) {
    const float* dw = (const float*)d_in[1 + 6 * h + 2];
    const float* db = (const float*)d_in[1 + 6 * h + 3];
    const float* pw = (const float*)d_in[1 + 6 * h + 4];
    const float* pb = (const float*)d_in[1 + 6 * h + 5];
    const short* ch = ceh + h * 131072;
    const short* cl = cel + h * 131072;
    const int C = Cs[h], CP = CPs[h], SG = SGs[h], CPB = CPBs[h];

    s_mfma<<<dim3(512, 2), 256, 0, stream>>>(xh, xl, awh + h * 32768, awl + h * 32768,
                                             prevb, sGh, sGl, h > 0 ? 1 : 0);
    mfma_colP<<<dim3(512, SG), 256, 0, stream>>>(sGh, sGl, ch, cl, partial, Pb, CPB, CP);
    wz_kernel<<<128, 256, 0, stream>>>(partial, Zb, wb, C);
    rowpass_k<<<RT / 4, 256, 0, stream>>>(Pb, wb, h > 0 ? prevb : nullptr, gs, CP);
    pooled_partial_k<<<dim3(8, NB), 256, 0, stream>>>(xh, gs, pp);
    pooled_dense_k<<<NB, 256, 0, stream>>>(pp, tm, dw, db, dense);
    pred_k<<<NB, 256, 0, stream>>>(dense, pw, pb, Zb, (float*)d_out + outoff[h], wb, C,
                                   h < 2 ? 1 : 0);
    if (h < 2)
      rowpass_k<<<RT / 4, 256, 0, stream>>>(Pb, wb, nullptr, prevb, CP);
  }
}

// Round 14
// 525.907 us; speedup vs baseline: 1.2459x; 1.0492x over previous
//
#include <hip/hip_runtime.h>
#include <math.h>

#define LSEQ 2048
#define NB   32
#define DM   256
#define RT   65536   // total rows B*L
#define LDT  84      // P-transpose LDS row stride (shorts); 84 -> 4-row step ≡ 8 banks (2-way, free)

// XOR slot swizzle: 8-elem block q of row c stored at slot SW8(c,q) (involution)
#define SW8(c, q) (((q) & 8) | (((q) ^ (c)) & 7))

typedef float f4 __attribute__((ext_vector_type(4)));
typedef __attribute__((ext_vector_type(4))) float f32x4;
typedef __attribute__((ext_vector_type(8))) short bf16x8;

#define MFMA16 __builtin_amdgcn_mfma_f32_16x16x32_bf16

// ---- bf16 helpers (bit-level, RNE) ----------------------------------------

__device__ __forceinline__ short f2bf(float f) {
  unsigned u = __float_as_uint(f);
  unsigned r = (u + 0x7fffu + ((u >> 16) & 1u)) >> 16;
  return (short)r;
}
__device__ __forceinline__ float bf2f(short s) {
  return __uint_as_float(((unsigned)(unsigned short)s) << 16);
}
__device__ __forceinline__ float tanh_fast(float z) {
  float e = __expf(2.f * z);
  return 1.f - __fdividef(2.f, 1.f + e);
}

// ---- x -> split bf16 + text_mean partial (fused, x read once) -------------

__global__ __launch_bounds__(256) void cvt_x_tm(const float* __restrict__ x,
                                                short* __restrict__ xh,
                                                short* __restrict__ xl,
                                                float* __restrict__ tp) {
  int lc = blockIdx.x, b = blockIdx.y, d = threadIdx.x;
  long rbase = (long)b * LSEQ + lc * 128;
  const float* xp = x + rbase * DM + d;
  short* xhp = xh + rbase * DM + d;
  short* xlp = xl + rbase * DM + d;
  float a = 0.f;
#pragma unroll 4
  for (int i = 0; i < 128; ++i) {
    float v = xp[(long)i * DM];
    a += v;
    short hh = f2bf(v);
    xhp[(long)i * DM] = hh;
    xlp[(long)i * DM] = f2bf(v - bf2f(hh));
  }
  tp[((long)lc * NB + b) * DM + d] = a;
}

__global__ __launch_bounds__(256) void tm_reduce_k(const float* __restrict__ tp,
                                                   float* __restrict__ tm) {
  int idx = blockIdx.x * 256 + threadIdx.x;   // < 8192
  int b = idx >> 8, d = idx & 255;
  float a = 0.f;
#pragma unroll
  for (int lc = 0; lc < 16; ++lc) a += tp[((long)lc * NB + b) * DM + d];
  tm[idx] = a * (1.f / LSEQ);
}

// ---- weight conversions to split-bf16 -------------------------------------

__global__ __launch_bounds__(256) void cvt_ce(const float* __restrict__ ce,
                                              short* __restrict__ h,
                                              short* __restrict__ l, int C) {
  int idx = blockIdx.x * 256 + threadIdx.x;   // < 131072, [c][128k]
  int c = idx >> 7, k = idx & 127;
  float v = (c < C && k < 100) ? ce[c * 100 + k] : 0.f;
  short hh = f2bf(v);
  h[idx] = hh;
  l[idx] = f2bf(v - bf2f(hh));
}

__global__ __launch_bounds__(256) void cvt_aw(const float* __restrict__ aw,
                                              short* __restrict__ h,
                                              short* __restrict__ l) {
  int idx = blockIdx.x * 256 + threadIdx.x;   // < 32768, [e][256k]
  int e = idx >> 8, k = idx & 255;
  float v = (e < 100) ? aw[k * 100 + e] : 0.f;
  short hh = f2bf(v);
  h[idx] = hh;
  l[idx] = f2bf(v - bf2f(hh));
}

// ---- s_mfma (R10 version): grid (512,2); 4 waves x 32 rows; ONE 64-e strip
// per block; aw staged in LDS per k-half. acc[2][4]=32 regs -> no spill.

__global__ __launch_bounds__(256) void s_mfma(const short* __restrict__ xh,
                                              const short* __restrict__ xl,
                                              const short* __restrict__ awh,
                                              const short* __restrict__ awl,
                                              const float* __restrict__ prevb,
                                              short* __restrict__ sGh,
                                              short* __restrict__ sGl, int hasPrev) {
  __shared__ __align__(16) short bufh[8192];   // 64 e x 128 k, swizzled slots
  __shared__ __align__(16) short bufl[8192];
  const int tid = threadIdx.x, lane = tid & 63, wv = tid >> 6;
  const int lo = lane & 15, hi = lane >> 4;
  const int st = blockIdx.y;
  const long r0 = (long)blockIdx.x * 128 + wv * 32;

  float pv[2][4];
#pragma unroll
  for (int m = 0; m < 2; ++m)
#pragma unroll
    for (int q = 0; q < 4; ++q)
      pv[m][q] = hasPrev ? prevb[r0 + m * 16 + hi * 4 + q] : 1.f;

  f32x4 acc[2][4];
#pragma unroll
  for (int m = 0; m < 2; ++m)
#pragma unroll
    for (int n = 0; n < 4; ++n) acc[m][n] = (f32x4){0.f, 0.f, 0.f, 0.f};

#pragma unroll 1
  for (int kh = 0; kh < 2; ++kh) {
    __syncthreads();
    {  // stage aw strip rows e=0..63 of half kh (16KB hi + 16KB lo), swizzled
      const short* gh = awh + (long)st * 64 * 256 + kh * 128;
      const short* gl = awl + (long)st * 64 * 256 + kh * 128;
#pragma unroll
      for (int j = 0; j < 4; ++j) {
        int slot = tid + j * 256;
        int c = slot >> 4, q = slot & 15;
        int dst = c * 128 + SW8(c, q) * 8;
        *(bf16x8*)(bufh + dst) = *(const bf16x8*)(gh + (long)c * 256 + q * 8);
        *(bf16x8*)(bufl + dst) = *(const bf16x8*)(gl + (long)c * 256 + q * 8);
      }
    }
    // A fragments for this k-half (global, coalesced 16B/lane)
    bf16x8 Ah[2][4], Al[2][4];
#pragma unroll
    for (int m = 0; m < 2; ++m)
#pragma unroll
      for (int ks = 0; ks < 4; ++ks) {
        long off = (r0 + m * 16 + lo) * 256 + kh * 128 + ks * 32 + hi * 8;
        Ah[m][ks] = *(const bf16x8*)(xh + off);
        Al[m][ks] = *(const bf16x8*)(xl + off);
      }
    __syncthreads();
#pragma unroll
    for (int ks = 0; ks < 4; ++ks) {
      bf16x8 Bh[4], Bl[4];
#pragma unroll
      for (int n = 0; n < 4; ++n) {
        int c = n * 16 + lo;
        int idx = c * 128 + SW8(c, ks * 4 + hi) * 8;
        Bh[n] = *(const bf16x8*)(bufh + idx);
        Bl[n] = *(const bf16x8*)(bufl + idx);
      }
#pragma unroll
      for (int n = 0; n < 4; ++n) {
        acc[0][n] = MFMA16(Ah[0][ks], Bh[n], acc[0][n], 0, 0, 0);
        acc[1][n] = MFMA16(Ah[1][ks], Bh[n], acc[1][n], 0, 0, 0);
        acc[0][n] = MFMA16(Al[0][ks], Bh[n], acc[0][n], 0, 0, 0);
        acc[1][n] = MFMA16(Al[1][ks], Bh[n], acc[1][n], 0, 0, 0);
        acc[0][n] = MFMA16(Ah[0][ks], Bl[n], acc[0][n], 0, 0, 0);
        acc[1][n] = MFMA16(Ah[1][ks], Bl[n], acc[1][n], 0, 0, 0);
      }
    }
  }

#pragma unroll
  for (int m = 0; m < 2; ++m)
#pragma unroll
    for (int n = 0; n < 4; ++n)
#pragma unroll
      for (int q = 0; q < 4; ++q) {
        long r = r0 + m * 16 + hi * 4 + q;
        int c = st * 64 + n * 16 + lo;
        float t = tanh_fast(pv[m][q] * acc[m][n][q]);
        short hh = f2bf(t);
        sGh[r * 128 + c] = hh;
        sGl[r * 128 + c] = f2bf(t - bf2f(hh));
      }
}

// ---- A-fragment load (resident) -------------------------------------------

__device__ __forceinline__ void load_afrags(const short* __restrict__ sGh,
                                            const short* __restrict__ sGl,
                                            long r0, int lo, int hi,
                                            bf16x8 (&Ah)[2][4], bf16x8 (&Al)[2][4]) {
#pragma unroll
  for (int m = 0; m < 2; ++m)
#pragma unroll
    for (int ks = 0; ks < 4; ++ks) {
      long off = (r0 + m * 16 + lo) * 128 + ks * 32 + hi * 8;
      Ah[m][ks] = *(const bf16x8*)(sGh + off);
      Al[m][ks] = *(const bf16x8*)(sGl + off);
    }
}

// ---- mfma_colP: LDS-staged ce GEMM + col partials + P=exp bf16 ------------
// grid (512, SG); transpose-LDS aliased over staging buffers (32KB total)

__global__ __launch_bounds__(256) void mfma_colP(const short* __restrict__ sGh,
                                                 const short* __restrict__ sGl,
                                                 const short* __restrict__ ceh,
                                                 const short* __restrict__ cel,
                                                 float* __restrict__ partial,
                                                 short* __restrict__ P,
                                                 int cpb, int CP) {
  __shared__ __align__(16) short smem[16384];   // bufh | bufl, tlds aliased
  short* bufh = smem;
  short* bufl = smem + 8192;
  const int tid = threadIdx.x, lane = tid & 63, wv = tid >> 6;
  const int lo = lane & 15, hi = lane >> 4;
  const long r0 = (long)blockIdx.x * 128 + wv * 32;
  const long gw = (long)blockIdx.x * 4 + wv;
  const int s0 = blockIdx.y * cpb;
  const int oct = lane & 7;
  short* tw = smem + wv * (32 * LDT);   // per-wave transpose region (aliased, 21.5KB)

  bf16x8 Ah[2][4], Al[2][4];
  load_afrags(sGh, sGl, r0, lo, hi, Ah, Al);

#pragma unroll 1
  for (int s = 0; s < cpb; ++s) {
    const int c0s = (s0 + s) * 64;
    __syncthreads();   // prior epilogue (tlds) done -> buf reusable
    {  // stage ce strip (64 cols x 128 k), hi + lo, swizzled
      const short* gh = ceh + (long)c0s * 128;
      const short* gl = cel + (long)c0s * 128;
#pragma unroll
      for (int j = 0; j < 4; ++j) {
        int slot = tid + j * 256;
        int c = slot >> 4, q = slot & 15;
        int dst = c * 128 + SW8(c, q) * 8;
        *(bf16x8*)(bufh + dst) = *(const bf16x8*)(gh + slot * 8);
        *(bf16x8*)(bufl + dst) = *(const bf16x8*)(gl + slot * 8);
      }
    }
    __syncthreads();   // buf ready

    f32x4 acc[2][4];
#pragma unroll
    for (int m = 0; m < 2; ++m)
#pragma unroll
      for (int n = 0; n < 4; ++n) acc[m][n] = (f32x4){0.f, 0.f, 0.f, 0.f};

#pragma unroll
    for (int ks = 0; ks < 4; ++ks) {
      bf16x8 Bh[4], Bl[4];
#pragma unroll
      for (int n = 0; n < 4; ++n) {
        int c = n * 16 + lo;
        int idx = c * 128 + SW8(c, ks * 4 + hi) * 8;
        Bh[n] = *(const bf16x8*)(bufh + idx);
        Bl[n] = *(const bf16x8*)(bufl + idx);
      }
#pragma unroll
      for (int n = 0; n < 4; ++n) {
        acc[0][n] = MFMA16(Ah[0][ks], Bh[n], acc[0][n], 0, 0, 0);
        acc[1][n] = MFMA16(Ah[1][ks], Bh[n], acc[1][n], 0, 0, 0);
        acc[0][n] = MFMA16(Al[0][ks], Bh[n], acc[0][n], 0, 0, 0);
        acc[1][n] = MFMA16(Al[1][ks], Bh[n], acc[1][n], 0, 0, 0);
        acc[0][n] = MFMA16(Ah[0][ks], Bl[n], acc[0][n], 0, 0, 0);
        acc[1][n] = MFMA16(Ah[1][ks], Bl[n], acc[1][n], 0, 0, 0);
      }
    }
    __syncthreads();   // all B-frag reads done -> buf dead, tlds may overwrite

    // epilogue: exp -> col partial + per-wave LDS transpose for P stores
#pragma unroll
    for (int n = 0; n < 4; ++n) {
      float sum = 0.f;
#pragma unroll
      for (int m = 0; m < 2; ++m)
#pragma unroll
        for (int q = 0; q < 4; ++q) {
          float e = __expf(acc[m][n][q]);
          sum += e;
          tw[(m * 16 + hi * 4 + q) * LDT + n * 16 + lo] = f2bf(e);
        }
      sum += __shfl_xor(sum, 16);
      sum += __shfl_xor(sum, 32);
      if (lane < 16) partial[gw * 1024 + c0s + n * 16 + lane] = sum;
    }
#pragma unroll
    for (int j = 0; j < 4; ++j) {
      int rl = (lane >> 3) + j * 8;
      bf16x8 v = *(const bf16x8*)(&tw[rl * LDT + oct * 8]);
      *(bf16x8*)(P + (r0 + rl) * (long)CP + c0s + oct * 8) = v;
    }
  }
}

// ---- wz: Z = sum of 64 wave partials per batch; w = 1/(C*Z) ---------------

__global__ __launch_bounds__(256) void wz_kernel(const float* __restrict__ partial,
                                                 float* __restrict__ Z,
                                                 float* __restrict__ w, int C) {
  int idx = blockIdx.x * 256 + threadIdx.x;  // < 32768
  int b = idx >> 10, c = idx & 1023;
  float z = 0.f;
#pragma unroll 8
  for (int i = 0; i < 64; ++i) z += partial[(long)(b * 64 + i) * 1024 + c];
  Z[idx] = z;
  w[idx] = (c < C) ? 1.f / ((float)C * z) : 0.f;
}

// ---- rowpass: out[r] = (ps[r]?) * sum_c P[r][c]*w[c]  (wave per row) ------

__global__ __launch_bounds__(256) void rowpass_k(const short* __restrict__ P,
                                                 const float* __restrict__ w,
                                                 const float* __restrict__ ps,
                                                 float* __restrict__ out, int CP) {
  const int lane = threadIdx.x & 63, wv = threadIdx.x >> 6;
  const long r = (long)blockIdx.x * 4 + wv;
  const int b = (int)(r >> 11);
  const short* Pr = P + r * (long)CP;
  const float* wb_ = w + b * 1024;
  float acc = 0.f;
  for (int c0 = lane * 8; c0 < CP; c0 += 512) {
    bf16x8 pv = *(const bf16x8*)(Pr + c0);
    f4 w0 = *(const f4*)(wb_ + c0);
    f4 w1 = *(const f4*)(wb_ + c0 + 4);
    acc = fmaf(bf2f(pv[0]), w0[0], acc);
    acc = fmaf(bf2f(pv[1]), w0[1], acc);
    acc = fmaf(bf2f(pv[2]), w0[2], acc);
    acc = fmaf(bf2f(pv[3]), w0[3], acc);
    acc = fmaf(bf2f(pv[4]), w1[0], acc);
    acc = fmaf(bf2f(pv[5]), w1[1], acc);
    acc = fmaf(bf2f(pv[6]), w1[2], acc);
    acc = fmaf(bf2f(pv[7]), w1[3], acc);
  }
  acc += __shfl_xor(acc, 1);
  acc += __shfl_xor(acc, 2);
  acc += __shfl_xor(acc, 4);
  acc += __shfl_xor(acc, 8);
  acc += __shfl_xor(acc, 16);
  acc += __shfl_xor(acc, 32);
  if (lane == 0) out[r] = ps ? acc * ps[r] : acc;
}

// ---- pooled = sum_l gs[b,l]*x[b,l,:]  (coalesced ushort2 reads) -----------

__global__ __launch_bounds__(256) void pooled_partial_k(const short* __restrict__ xh,
                                                        const float* __restrict__ gs,
                                                        float* __restrict__ pp) {
  int lc = blockIdx.x, b = blockIdx.y;
  int rr = threadIdx.x >> 7, dd = threadIdx.x & 127;
  long rbase = (long)b * LSEQ + lc * 256 + rr * 128;
  const short* xp = xh + rbase * DM + dd * 2;
  const float* gp = gs + rbase;
  float a0 = 0.f, a1 = 0.f;
#pragma unroll 4
  for (int i = 0; i < 128; ++i) {
    unsigned v = *(const unsigned*)(xp + (long)i * DM);
    float g = gp[i];
    a0 = fmaf(g, __uint_as_float((v & 0xffffu) << 16), a0);
    a1 = fmaf(g, __uint_as_float(v & 0xffff0000u), a1);
  }
  float* dst = pp + ((long)(lc * 2 + rr) * NB + b) * DM + dd * 2;
  dst[0] = a0;
  dst[1] = a1;
}

__global__ __launch_bounds__(256) void pooled_reduce_k(const float* __restrict__ pp,
                                                       float* __restrict__ pooled) {
  int idx = blockIdx.x * 256 + threadIdx.x;  // < 8192
  int b = idx >> 8, d = idx & 255;
  float a = 0.f;
#pragma unroll
  for (int lc = 0; lc < 16; ++lc) a += pp[((long)lc * NB + b) * DM + d];
  pooled[idx] = a;
}

// ---- dense = relu([tm, pooled] @ dw + db) ---------------------------------

__global__ __launch_bounds__(256) void dense_k(const float* __restrict__ tm,
                                               const float* __restrict__ pooled,
                                               const float* __restrict__ dw,
                                               const float* __restrict__ db,
                                               float* __restrict__ dense) {
  __shared__ float f[2 * DM];
  int b = blockIdx.x, t = threadIdx.x;
  f[t] = tm[b * DM + t];
  f[DM + t] = pooled[b * DM + t];
  __syncthreads();
  float a = db[t];
#pragma unroll 8
  for (int k = 0; k < 2 * DM; ++k) a = fmaf(f[k], dw[(long)k * DM + t], a);
  dense[b * DM + t] = fmaxf(a, 0.f);
}

// ---- logits = dense @ pw + pb ---------------------------------------------

__global__ __launch_bounds__(256) void logits_k(const float* __restrict__ dense,
                                                const float* __restrict__ pw,
                                                const float* __restrict__ pb,
                                                float* __restrict__ logits, int C) {
  __shared__ float dS[DM];
  int b = blockIdx.y, t = threadIdx.x;
  int c = blockIdx.x * 256 + t;
  dS[t] = dense[b * DM + t];
  __syncthreads();
  if (c < C) {
    float a = pb[c];
#pragma unroll 8
    for (int k = 0; k < DM; ++k) a = fmaf(dS[k], pw[(long)k * C + c], a);
    logits[b * 1024 + c] = a;
  }
}

// ---- softmax over C, write pred, optionally w3 = pred/(C*Z) ---------------

__global__ __launch_bounds__(256) void softmax_k(const float* __restrict__ logits,
                                                 const float* __restrict__ Z,
                                                 float* __restrict__ out,
                                                 float* __restrict__ w,
                                                 int C, int writeW) {
  __shared__ float buf[1024];
  __shared__ float red[256];
  int b = blockIdx.x, t = threadIdx.x;
  float m = -1e30f;
  for (int c = t; c < C; c += 256) {
    float v = logits[b * 1024 + c];
    buf[c] = v;
    m = fmaxf(m, v);
  }
  red[t] = m;
  __syncthreads();
  for (int s2 = 128; s2 > 0; s2 >>= 1) {
    if (t < s2) red[t] = fmaxf(red[t], red[t + s2]);
    __syncthreads();
  }
  m = red[0];
  __syncthreads();
  float sum = 0.f;
  for (int c = t; c < C; c += 256) {
    float e = __expf(buf[c] - m);
    buf[c] = e;
    sum += e;
  }
  red[t] = sum;
  __syncthreads();
  for (int s2 = 128; s2 > 0; s2 >>= 1) {
    if (t < s2) red[t] += red[t + s2];
    __syncthreads();
  }
  float inv = 1.f / red[0];
  for (int c = t; c < C; c += 256) out[(long)b * C + c] = buf[c] * inv;
  if (writeW) {
    float invC = 1.f / (float)C;
    for (int c = t; c < 1024; c += 256)
      w[b * 1024 + c] = (c < C) ? (buf[c] * inv) * invC / Z[b * 1024 + c] : 0.f;
  }
}

// ---- host -----------------------------------------------------------------

extern "C" void kernel_launch(void* const* d_in, const int* in_sizes, int n_in,
                              void* d_out, int out_size, void* d_ws, size_t ws_size,
                              hipStream_t stream) {
  (void)in_sizes; (void)n_in; (void)out_size; (void)ws_size;
  const float* x = (const float*)d_in[0];

  const int Cs[3]     = {21, 191, 1009};
  const int CPs[3]    = {64, 192, 1024};  // padded P row length
  const int SGs[3]    = {1, 1, 2};        // strip-groups (grid.y)
  const int CPBs[3]   = {1, 3, 8};        // strips per block; SG*CPB*64 == CP
  const int outoff[3] = {0, 672, 6784};

  char* base = (char*)d_ws;
  short* xh  = (short*)base; base += (size_t)RT * 256 * 2;
  short* xl  = (short*)base; base += (size_t)RT * 256 * 2;
  short* sGh = (short*)base; base += (size_t)RT * 128 * 2;
  short* sGl = (short*)base; base += (size_t)RT * 128 * 2;
  short* Pb  = (short*)base; base += (size_t)RT * 1024 * 2;   // P bf16
  short* ceh = (short*)base; base += (size_t)3 * 131072 * 2;
  short* cel = (short*)base; base += (size_t)3 * 131072 * 2;
  short* awh = (short*)base; base += (size_t)3 * 32768 * 2;
  short* awl = (short*)base; base += (size_t)3 * 32768 * 2;
  float* partial = (float*)base; base += (size_t)2048 * 1024 * 4;
  float* Zb     = (float*)base; base += 32768 * 4;
  float* wb     = (float*)base; base += 32768 * 4;
  float* gs     = (float*)base; base += RT * 4;
  float* prevb  = (float*)base; base += RT * 4;
  float* tp     = (float*)base; base += 131072 * 4;
  float* tm     = (float*)base; base += 8192 * 4;
  float* pp     = (float*)base; base += 131072 * 4;
  float* pooled = (float*)base; base += 8192 * 4;
  float* dense  = (float*)base; base += 8192 * 4;
  float* logits = (float*)base; base += 32768 * 4;

  cvt_x_tm<<<dim3(16, NB), 256, 0, stream>>>(x, xh, xl, tp);
  tm_reduce_k<<<32, 256, 0, stream>>>(tp, tm);
  for (int h = 0; h < 3; ++h) {
    cvt_ce<<<512, 256, 0, stream>>>((const float*)d_in[1 + 6 * h], ceh + h * 131072,
                                    cel + h * 131072, Cs[h]);
    cvt_aw<<<128, 256, 0, stream>>>((const float*)d_in[1 + 6 * h + 1], awh + h * 32768,
                                    awl + h * 32768);
  }

  for (int h = 0; h < 3; ++h) {
    const float* dw = (const float*)d_in[1 + 6 * h + 2];
    const float* db = (const float*)d_in[1 + 6 * h + 3];
    const float* pw = (const float*)d_in[1 + 6 * h + 4];
    const float* pb = (const float*)d_in[1 + 6 * h + 5];
    const short* ch = ceh + h * 131072;
    const short* cl = cel + h * 131072;
    const int C = Cs[h], CP = CPs[h], SG = SGs[h], CPB = CPBs[h];

    s_mfma<<<dim3(512, 2), 256, 0, stream>>>(xh, xl, awh + h * 32768, awl + h * 32768,
                                             prevb, sGh, sGl, h > 0 ? 1 : 0);
    mfma_colP<<<dim3(512, SG), 256, 0, stream>>>(sGh, sGl, ch, cl, partial, Pb, CPB, CP);
    wz_kernel<<<128, 256, 0, stream>>>(partial, Zb, wb, C);
    rowpass_k<<<RT / 4, 256, 0, stream>>>(Pb, wb, h > 0 ? prevb : nullptr, gs, CP);
    pooled_partial_k<<<dim3(8, NB), 256, 0, stream>>>(xh, gs, pp);
    pooled_reduce_k<<<32, 256, 0, stream>>>(pp, pooled);
    dense_k<<<NB, 256, 0, stream>>>(tm, pooled, dw, db, dense);
    logits_k<<<dim3((C + 255) / 256, NB), 256, 0, stream>>>(dense, pw, pb, logits, C);
    softmax_k<<<NB, 256, 0, stream>>>(logits, Zb, (float*)d_out + outoff[h], wb, C,
                                      h < 2 ? 1 : 0);
    if (h < 2)
      rowpass_k<<<RT / 4, 256, 0, stream>>>(Pb, wb, nullptr, prevb, CP);
  }
}

// Round 15
// 507.655 us; speedup vs baseline: 1.2907x; 1.0360x over previous
//
#include <hip/hip_runtime.h>
#include <math.h>

#define LSEQ 2048
#define NB   32
#define DM   256
#define RT   65536   // total rows B*L
#define LDT  88      // P-transpose LDS stride: 176B row = 11x16 (b128-aligned);
                     // 4-row step ≡ 16 banks mod 32 -> 4-way stores (was 8-way @80);
                     // read offsets rl*12 mod 32 all distinct -> uniform banks

// XOR slot swizzle: 8-elem block q of row c stored at slot SW8(c,q) (involution)
#define SW8(c, q) (((q) & 8) | (((q) ^ (c)) & 7))

typedef float f4 __attribute__((ext_vector_type(4)));
typedef __attribute__((ext_vector_type(4))) float f32x4;
typedef __attribute__((ext_vector_type(8))) short bf16x8;

#define MFMA16 __builtin_amdgcn_mfma_f32_16x16x32_bf16

// ---- bf16 helpers (bit-level, RNE) ----------------------------------------

__device__ __forceinline__ short f2bf(float f) {
  unsigned u = __float_as_uint(f);
  unsigned r = (u + 0x7fffu + ((u >> 16) & 1u)) >> 16;
  return (short)r;
}
__device__ __forceinline__ float bf2f(short s) {
  return __uint_as_float(((unsigned)(unsigned short)s) << 16);
}
__device__ __forceinline__ float tanh_fast(float z) {
  float e = __expf(2.f * z);
  return 1.f - __fdividef(2.f, 1.f + e);
}

// ---- x -> split bf16 + text_mean partial (fused, x read once) -------------

__global__ __launch_bounds__(256) void cvt_x_tm(const float* __restrict__ x,
                                                short* __restrict__ xh,
                                                short* __restrict__ xl,
                                                float* __restrict__ tp) {
  int lc = blockIdx.x, b = blockIdx.y, d = threadIdx.x;
  long rbase = (long)b * LSEQ + lc * 128;
  const float* xp = x + rbase * DM + d;
  short* xhp = xh + rbase * DM + d;
  short* xlp = xl + rbase * DM + d;
  float a = 0.f;
#pragma unroll 4
  for (int i = 0; i < 128; ++i) {
    float v = xp[(long)i * DM];
    a += v;
    short hh = f2bf(v);
    xhp[(long)i * DM] = hh;
    xlp[(long)i * DM] = f2bf(v - bf2f(hh));
  }
  tp[((long)lc * NB + b) * DM + d] = a;
}

__global__ __launch_bounds__(256) void tm_reduce_k(const float* __restrict__ tp,
                                                   float* __restrict__ tm) {
  int idx = blockIdx.x * 256 + threadIdx.x;   // < 8192
  int b = idx >> 8, d = idx & 255;
  float a = 0.f;
#pragma unroll
  for (int lc = 0; lc < 16; ++lc) a += tp[((long)lc * NB + b) * DM + d];
  tm[idx] = a * (1.f / LSEQ);
}

// ---- weight conversions to split-bf16 (batched over all 3 levels) ---------

__global__ __launch_bounds__(256) void cvt_ce_all(const float* __restrict__ ce0,
                                                  const float* __restrict__ ce1,
                                                  const float* __restrict__ ce2,
                                                  short* __restrict__ h,
                                                  short* __restrict__ l) {
  int hh_ = blockIdx.y;
  const float* ce = hh_ == 0 ? ce0 : (hh_ == 1 ? ce1 : ce2);
  int C = hh_ == 0 ? 21 : (hh_ == 1 ? 191 : 1009);
  int idx = blockIdx.x * 256 + threadIdx.x;   // < 131072, [c][128k]
  int c = idx >> 7, k = idx & 127;
  float v = (c < C && k < 100) ? ce[c * 100 + k] : 0.f;
  short hv = f2bf(v);
  h[hh_ * 131072 + idx] = hv;
  l[hh_ * 131072 + idx] = f2bf(v - bf2f(hv));
}

__global__ __launch_bounds__(256) void cvt_aw_all(const float* __restrict__ aw0,
                                                  const float* __restrict__ aw1,
                                                  const float* __restrict__ aw2,
                                                  short* __restrict__ h,
                                                  short* __restrict__ l) {
  int hh_ = blockIdx.y;
  const float* aw = hh_ == 0 ? aw0 : (hh_ == 1 ? aw1 : aw2);
  int idx = blockIdx.x * 256 + threadIdx.x;   // < 32768, [e][256k]
  int e = idx >> 8, k = idx & 255;
  float v = (e < 100) ? aw[k * 100 + e] : 0.f;
  short hv = f2bf(v);
  h[hh_ * 32768 + idx] = hv;
  l[hh_ * 32768 + idx] = f2bf(v - bf2f(hv));
}

// ---- s_mfma (R10 version): grid (512,2); 4 waves x 32 rows; ONE 64-e strip
// per block; aw staged in LDS per k-half. acc[2][4]=32 regs -> no spill.

__global__ __launch_bounds__(256) void s_mfma(const short* __restrict__ xh,
                                              const short* __restrict__ xl,
                                              const short* __restrict__ awh,
                                              const short* __restrict__ awl,
                                              const float* __restrict__ prevb,
                                              short* __restrict__ sGh,
                                              short* __restrict__ sGl, int hasPrev) {
  __shared__ __align__(16) short bufh[8192];   // 64 e x 128 k, swizzled slots
  __shared__ __align__(16) short bufl[8192];
  const int tid = threadIdx.x, lane = tid & 63, wv = tid >> 6;
  const int lo = lane & 15, hi = lane >> 4;
  const int st = blockIdx.y;
  const long r0 = (long)blockIdx.x * 128 + wv * 32;

  float pv[2][4];
#pragma unroll
  for (int m = 0; m < 2; ++m)
#pragma unroll
    for (int q = 0; q < 4; ++q)
      pv[m][q] = hasPrev ? prevb[r0 + m * 16 + hi * 4 + q] : 1.f;

  f32x4 acc[2][4];
#pragma unroll
  for (int m = 0; m < 2; ++m)
#pragma unroll
    for (int n = 0; n < 4; ++n) acc[m][n] = (f32x4){0.f, 0.f, 0.f, 0.f};

#pragma unroll 1
  for (int kh = 0; kh < 2; ++kh) {
    __syncthreads();
    {  // stage aw strip rows e=0..63 of half kh (16KB hi + 16KB lo), swizzled
      const short* gh = awh + (long)st * 64 * 256 + kh * 128;
      const short* gl = awl + (long)st * 64 * 256 + kh * 128;
#pragma unroll
      for (int j = 0; j < 4; ++j) {
        int slot = tid + j * 256;
        int c = slot >> 4, q = slot & 15;
        int dst = c * 128 + SW8(c, q) * 8;
        *(bf16x8*)(bufh + dst) = *(const bf16x8*)(gh + (long)c * 256 + q * 8);
        *(bf16x8*)(bufl + dst) = *(const bf16x8*)(gl + (long)c * 256 + q * 8);
      }
    }
    // A fragments for this k-half (global, coalesced 16B/lane)
    bf16x8 Ah[2][4], Al[2][4];
#pragma unroll
    for (int m = 0; m < 2; ++m)
#pragma unroll
      for (int ks = 0; ks < 4; ++ks) {
        long off = (r0 + m * 16 + lo) * 256 + kh * 128 + ks * 32 + hi * 8;
        Ah[m][ks] = *(const bf16x8*)(xh + off);
        Al[m][ks] = *(const bf16x8*)(xl + off);
      }
    __syncthreads();
#pragma unroll
    for (int ks = 0; ks < 4; ++ks) {
      bf16x8 Bh[4], Bl[4];
#pragma unroll
      for (int n = 0; n < 4; ++n) {
        int c = n * 16 + lo;
        int idx = c * 128 + SW8(c, ks * 4 + hi) * 8;
        Bh[n] = *(const bf16x8*)(bufh + idx);
        Bl[n] = *(const bf16x8*)(bufl + idx);
      }
#pragma unroll
      for (int n = 0; n < 4; ++n) {
        acc[0][n] = MFMA16(Ah[0][ks], Bh[n], acc[0][n], 0, 0, 0);
        acc[1][n] = MFMA16(Ah[1][ks], Bh[n], acc[1][n], 0, 0, 0);
        acc[0][n] = MFMA16(Al[0][ks], Bh[n], acc[0][n], 0, 0, 0);
        acc[1][n] = MFMA16(Al[1][ks], Bh[n], acc[1][n], 0, 0, 0);
        acc[0][n] = MFMA16(Ah[0][ks], Bl[n], acc[0][n], 0, 0, 0);
        acc[1][n] = MFMA16(Ah[1][ks], Bl[n], acc[1][n], 0, 0, 0);
      }
    }
  }

#pragma unroll
  for (int m = 0; m < 2; ++m)
#pragma unroll
    for (int n = 0; n < 4; ++n)
#pragma unroll
      for (int q = 0; q < 4; ++q) {
        long r = r0 + m * 16 + hi * 4 + q;
        int c = st * 64 + n * 16 + lo;
        float t = tanh_fast(pv[m][q] * acc[m][n][q]);
        short hh = f2bf(t);
        sGh[r * 128 + c] = hh;
        sGl[r * 128 + c] = f2bf(t - bf2f(hh));
      }
}

// ---- A-fragment load (resident) -------------------------------------------

__device__ __forceinline__ void load_afrags(const short* __restrict__ sGh,
                                            const short* __restrict__ sGl,
                                            long r0, int lo, int hi,
                                            bf16x8 (&Ah)[2][4], bf16x8 (&Al)[2][4]) {
#pragma unroll
  for (int m = 0; m < 2; ++m)
#pragma unroll
    for (int ks = 0; ks < 4; ++ks) {
      long off = (r0 + m * 16 + lo) * 128 + ks * 32 + hi * 8;
      Ah[m][ks] = *(const bf16x8*)(sGh + off);
      Al[m][ks] = *(const bf16x8*)(sGl + off);
    }
}

// ---- mfma_colP: LDS-staged ce GEMM + col partials + P=exp bf16 ------------
// grid (512, SG); transpose-LDS aliased over staging buffers (32KB total)

__global__ __launch_bounds__(256) void mfma_colP(const short* __restrict__ sGh,
                                                 const short* __restrict__ sGl,
                                                 const short* __restrict__ ceh,
                                                 const short* __restrict__ cel,
                                                 float* __restrict__ partial,
                                                 short* __restrict__ P,
                                                 int cpb, int CP) {
  __shared__ __align__(16) short smem[16384];   // bufh | bufl, tlds aliased
  short* bufh = smem;
  short* bufl = smem + 8192;
  const int tid = threadIdx.x, lane = tid & 63, wv = tid >> 6;
  const int lo = lane & 15, hi = lane >> 4;
  const long r0 = (long)blockIdx.x * 128 + wv * 32;
  const long gw = (long)blockIdx.x * 4 + wv;
  const int s0 = blockIdx.y * cpb;
  const int oct = lane & 7;
  short* tw = smem + wv * (32 * LDT);   // per-wave transpose region (aliased, 22.5KB)

  bf16x8 Ah[2][4], Al[2][4];
  load_afrags(sGh, sGl, r0, lo, hi, Ah, Al);

#pragma unroll 1
  for (int s = 0; s < cpb; ++s) {
    const int c0s = (s0 + s) * 64;
    __syncthreads();   // prior epilogue (tlds) done -> buf reusable
    {  // stage ce strip (64 cols x 128 k), hi + lo, swizzled
      const short* gh = ceh + (long)c0s * 128;
      const short* gl = cel + (long)c0s * 128;
#pragma unroll
      for (int j = 0; j < 4; ++j) {
        int slot = tid + j * 256;
        int c = slot >> 4, q = slot & 15;
        int dst = c * 128 + SW8(c, q) * 8;
        *(bf16x8*)(bufh + dst) = *(const bf16x8*)(gh + slot * 8);
        *(bf16x8*)(bufl + dst) = *(const bf16x8*)(gl + slot * 8);
      }
    }
    __syncthreads();   // buf ready

    f32x4 acc[2][4];
#pragma unroll
    for (int m = 0; m < 2; ++m)
#pragma unroll
      for (int n = 0; n < 4; ++n) acc[m][n] = (f32x4){0.f, 0.f, 0.f, 0.f};

#pragma unroll
    for (int ks = 0; ks < 4; ++ks) {
      bf16x8 Bh[4], Bl[4];
#pragma unroll
      for (int n = 0; n < 4; ++n) {
        int c = n * 16 + lo;
        int idx = c * 128 + SW8(c, ks * 4 + hi) * 8;
        Bh[n] = *(const bf16x8*)(bufh + idx);
        Bl[n] = *(const bf16x8*)(bufl + idx);
      }
#pragma unroll
      for (int n = 0; n < 4; ++n) {
        acc[0][n] = MFMA16(Ah[0][ks], Bh[n], acc[0][n], 0, 0, 0);
        acc[1][n] = MFMA16(Ah[1][ks], Bh[n], acc[1][n], 0, 0, 0);
        acc[0][n] = MFMA16(Al[0][ks], Bh[n], acc[0][n], 0, 0, 0);
        acc[1][n] = MFMA16(Al[1][ks], Bh[n], acc[1][n], 0, 0, 0);
        acc[0][n] = MFMA16(Ah[0][ks], Bl[n], acc[0][n], 0, 0, 0);
        acc[1][n] = MFMA16(Ah[1][ks], Bl[n], acc[1][n], 0, 0, 0);
      }
    }
    __syncthreads();   // all B-frag reads done -> buf dead, tlds may overwrite

    // epilogue: exp -> col partial + per-wave LDS transpose for P stores
#pragma unroll
    for (int n = 0; n < 4; ++n) {
      float sum = 0.f;
#pragma unroll
      for (int m = 0; m < 2; ++m)
#pragma unroll
        for (int q = 0; q < 4; ++q) {
          float e = __expf(acc[m][n][q]);
          sum += e;
          tw[(m * 16 + hi * 4 + q) * LDT + n * 16 + lo] = f2bf(e);
        }
      sum += __shfl_xor(sum, 16);
      sum += __shfl_xor(sum, 32);
      if (lane < 16) partial[gw * 1024 + c0s + n * 16 + lane] = sum;
    }
#pragma unroll
    for (int j = 0; j < 4; ++j) {
      int rl = (lane >> 3) + j * 8;
      bf16x8 v = *(const bf16x8*)(&tw[rl * LDT + oct * 8]);
      *(bf16x8*)(P + (r0 + rl) * (long)CP + c0s + oct * 8) = v;
    }
  }
}

// ---- wz: Z = sum of 64 wave partials per batch; w = 1/(C*Z) ---------------

__global__ __launch_bounds__(256) void wz_kernel(const float* __restrict__ partial,
                                                 float* __restrict__ Z,
                                                 float* __restrict__ w, int C) {
  int idx = blockIdx.x * 256 + threadIdx.x;  // < 32768
  int b = idx >> 10, c = idx & 1023;
  float z = 0.f;
#pragma unroll 8
  for (int i = 0; i < 64; ++i) z += partial[(long)(b * 64 + i) * 1024 + c];
  Z[idx] = z;
  w[idx] = (c < C) ? 1.f / ((float)C * z) : 0.f;
}

// ---- rowpass: out[r] = (ps[r]?) * sum_c P[r][c]*w[c]  (wave per row) ------

__global__ __launch_bounds__(256) void rowpass_k(const short* __restrict__ P,
                                                 const float* __restrict__ w,
                                                 const float* __restrict__ ps,
                                                 float* __restrict__ out, int CP) {
  const int lane = threadIdx.x & 63, wv = threadIdx.x >> 6;
  const long r = (long)blockIdx.x * 4 + wv;
  const int b = (int)(r >> 11);
  const short* Pr = P + r * (long)CP;
  const float* wb_ = w + b * 1024;
  float acc = 0.f;
  for (int c0 = lane * 8; c0 < CP; c0 += 512) {
    bf16x8 pv = *(const bf16x8*)(Pr + c0);
    f4 w0 = *(const f4*)(wb_ + c0);
    f4 w1 = *(const f4*)(wb_ + c0 + 4);
    acc = fmaf(bf2f(pv[0]), w0[0], acc);
    acc = fmaf(bf2f(pv[1]), w0[1], acc);
    acc = fmaf(bf2f(pv[2]), w0[2], acc);
    acc = fmaf(bf2f(pv[3]), w0[3], acc);
    acc = fmaf(bf2f(pv[4]), w1[0], acc);
    acc = fmaf(bf2f(pv[5]), w1[1], acc);
    acc = fmaf(bf2f(pv[6]), w1[2], acc);
    acc = fmaf(bf2f(pv[7]), w1[3], acc);
  }
  acc += __shfl_xor(acc, 1);
  acc += __shfl_xor(acc, 2);
  acc += __shfl_xor(acc, 4);
  acc += __shfl_xor(acc, 8);
  acc += __shfl_xor(acc, 16);
  acc += __shfl_xor(acc, 32);
  if (lane == 0) out[r] = ps ? acc * ps[r] : acc;
}

// ---- pooled = sum_l gs[b,l]*x[b,l,:]  (coalesced ushort2 reads) -----------

__global__ __launch_bounds__(256) void pooled_partial_k(const short* __restrict__ xh,
                                                        const float* __restrict__ gs,
                                                        float* __restrict__ pp) {
  int lc = blockIdx.x, b = blockIdx.y;
  int rr = threadIdx.x >> 7, dd = threadIdx.x & 127;
  long rbase = (long)b * LSEQ + lc * 256 + rr * 128;
  const short* xp = xh + rbase * DM + dd * 2;
  const float* gp = gs + rbase;
  float a0 = 0.f, a1 = 0.f;
#pragma unroll 4
  for (int i = 0; i < 128; ++i) {
    unsigned v = *(const unsigned*)(xp + (long)i * DM);
    float g = gp[i];
    a0 = fmaf(g, __uint_as_float((v & 0xffffu) << 16), a0);
    a1 = fmaf(g, __uint_as_float(v & 0xffff0000u), a1);
  }
  float* dst = pp + ((long)(lc * 2 + rr) * NB + b) * DM + dd * 2;
  dst[0] = a0;
  dst[1] = a1;
}

__global__ __launch_bounds__(256) void pooled_reduce_k(const float* __restrict__ pp,
                                                       float* __restrict__ pooled) {
  int idx = blockIdx.x * 256 + threadIdx.x;  // < 8192
  int b = idx >> 8, d = idx & 255;
  float a = 0.f;
#pragma unroll
  for (int lc = 0; lc < 16; ++lc) a += pp[((long)lc * NB + b) * DM + d];
  pooled[idx] = a;
}

// ---- dense = relu([tm, pooled] @ dw + db) ---------------------------------

__global__ __launch_bounds__(256) void dense_k(const float* __restrict__ tm,
                                               const float* __restrict__ pooled,
                                               const float* __restrict__ dw,
                                               const float* __restrict__ db,
                                               float* __restrict__ dense) {
  __shared__ float f[2 * DM];
  int b = blockIdx.x, t = threadIdx.x;
  f[t] = tm[b * DM + t];
  f[DM + t] = pooled[b * DM + t];
  __syncthreads();
  float a = db[t];
#pragma unroll 8
  for (int k = 0; k < 2 * DM; ++k) a = fmaf(f[k], dw[(long)k * DM + t], a);
  dense[b * DM + t] = fmaxf(a, 0.f);
}

// ---- logits = dense @ pw + pb ---------------------------------------------

__global__ __launch_bounds__(256) void logits_k(const float* __restrict__ dense,
                                                const float* __restrict__ pw,
                                                const float* __restrict__ pb,
                                                float* __restrict__ logits, int C) {
  __shared__ float dS[DM];
  int b = blockIdx.y, t = threadIdx.x;
  int c = blockIdx.x * 256 + t;
  dS[t] = dense[b * DM + t];
  __syncthreads();
  if (c < C) {
    float a = pb[c];
#pragma unroll 8
    for (int k = 0; k < DM; ++k) a = fmaf(dS[k], pw[(long)k * C + c], a);
    logits[b * 1024 + c] = a;
  }
}

// ---- softmax over C, write pred, optionally w3 = pred/(C*Z) ---------------

__global__ __launch_bounds__(256) void softmax_k(const float* __restrict__ logits,
                                                 const float* __restrict__ Z,
                                                 float* __restrict__ out,
                                                 float* __restrict__ w,
                                                 int C, int writeW) {
  __shared__ float buf[1024];
  __shared__ float red[256];
  int b = blockIdx.x, t = threadIdx.x;
  float m = -1e30f;
  for (int c = t; c < C; c += 256) {
    float v = logits[b * 1024 + c];
    buf[c] = v;
    m = fmaxf(m, v);
  }
  red[t] = m;
  __syncthreads();
  for (int s2 = 128; s2 > 0; s2 >>= 1) {
    if (t < s2) red[t] = fmaxf(red[t], red[t + s2]);
    __syncthreads();
  }
  m = red[0];
  __syncthreads();
  float sum = 0.f;
  for (int c = t; c < C; c += 256) {
    float e = __expf(buf[c] - m);
    buf[c] = e;
    sum += e;
  }
  red[t] = sum;
  __syncthreads();
  for (int s2 = 128; s2 > 0; s2 >>= 1) {
    if (t < s2) red[t] += red[t + s2];
    __syncthreads();
  }
  float inv = 1.f / red[0];
  for (int c = t; c < C; c += 256) out[(long)b * C + c] = buf[c] * inv;
  if (writeW) {
    float invC = 1.f / (float)C;
    for (int c = t; c < 1024; c += 256)
      w[b * 1024 + c] = (c < C) ? (buf[c] * inv) * invC / Z[b * 1024 + c] : 0.f;
  }
}

// ---- host -----------------------------------------------------------------

extern "C" void kernel_launch(void* const* d_in, const int* in_sizes, int n_in,
                              void* d_out, int out_size, void* d_ws, size_t ws_size,
                              hipStream_t stream) {
  (void)in_sizes; (void)n_in; (void)out_size; (void)ws_size;
  const float* x = (const float*)d_in[0];

  const int Cs[3]     = {21, 191, 1009};
  const int CPs[3]    = {64, 192, 1024};  // padded P row length
  const int SGs[3]    = {1, 1, 2};        // strip-groups (grid.y)
  const int CPBs[3]   = {1, 3, 8};        // strips per block; SG*CPB*64 == CP
  const int outoff[3] = {0, 672, 6784};

  char* base = (char*)d_ws;
  short* xh  = (short*)base; base += (size_t)RT * 256 * 2;
  short* xl  = (short*)base; base += (size_t)RT * 256 * 2;
  short* sGh = (short*)base; base += (size_t)RT * 128 * 2;
  short* sGl = (short*)base; base += (size_t)RT * 128 * 2;
  short* Pb  = (short*)base; base += (size_t)RT * 1024 * 2;   // P bf16
  short* ceh = (short*)base; base += (size_t)3 * 131072 * 2;
  short* cel = (short*)base; base += (size_t)3 * 131072 * 2;
  short* awh = (short*)base; base += (size_t)3 * 32768 * 2;
  short* awl = (short*)base; base += (size_t)3 * 32768 * 2;
  float* partial = (float*)base; base += (size_t)2048 * 1024 * 4;
  float* Zb     = (float*)base; base += 32768 * 4;
  float* wb     = (float*)base; base += 32768 * 4;
  float* gs     = (float*)base; base += RT * 4;
  float* prevb  = (float*)base; base += RT * 4;
  float* tp     = (float*)base; base += 131072 * 4;
  float* tm     = (float*)base; base += 8192 * 4;
  float* pp     = (float*)base; base += 131072 * 4;
  float* pooled = (float*)base; base += 8192 * 4;
  float* dense  = (float*)base; base += 8192 * 4;
  float* logits = (float*)base; base += 32768 * 4;

  cvt_x_tm<<<dim3(16, NB), 256, 0, stream>>>(x, xh, xl, tp);
  tm_reduce_k<<<32, 256, 0, stream>>>(tp, tm);
  cvt_ce_all<<<dim3(512, 3), 256, 0, stream>>>((const float*)d_in[1],
                                               (const float*)d_in[7],
                                               (const float*)d_in[13], ceh, cel);
  cvt_aw_all<<<dim3(128, 3), 256, 0, stream>>>((const float*)d_in[2],
                                               (const float*)d_in[8],
                                               (const float*)d_in[14], awh, awl);

  for (int h = 0; h < 3; ++h) {
    const float* dw = (const float*)d_in[1 + 6 * h + 2];
    const float* db = (const float*)d_in[1 + 6 * h + 3];
    const float* pw = (const float*)d_in[1 + 6 * h + 4];
    const float* pb = (const float*)d_in[1 + 6 * h + 5];
    const short* ch = ceh + h * 131072;
    const short* cl = cel + h * 131072;
    const int C = Cs[h], CP = CPs[h], SG = SGs[h], CPB = CPBs[h];

    s_mfma<<<dim3(512, 2), 256, 0, stream>>>(xh, xl, awh + h * 32768, awl + h * 32768,
                                             prevb, sGh, sGl, h > 0 ? 1 : 0);
    mfma_colP<<<dim3(512, SG), 256, 0, stream>>>(sGh, sGl, ch, cl, partial, Pb, CPB, CP);
    wz_kernel<<<128, 256, 0, stream>>>(partial, Zb, wb, C);
    rowpass_k<<<RT / 4, 256, 0, stream>>>(Pb, wb, h > 0 ? prevb : nullptr, gs, CP);
    pooled_partial_k<<<dim3(8, NB), 256, 0, stream>>>(xh, gs, pp);
    pooled_reduce_k<<<32, 256, 0, stream>>>(pp, pooled);
    dense_k<<<NB, 256, 0, stream>>>(tm, pooled, dw, db, dense);
    logits_k<<<dim3((C + 255) / 256, NB), 256, 0, stream>>>(dense, pw, pb, logits, C);
    softmax_k<<<NB, 256, 0, stream>>>(logits, Zb, (float*)d_out + outoff[h], wb, C,
                                      h < 2 ? 1 : 0);
    if (h < 2)
      rowpass_k<<<RT / 4, 256, 0, stream>>>(Pb, wb, nullptr, prevb, CP);
  }
}

// Round 16
// 497.701 us; speedup vs baseline: 1.3165x; 1.0200x over previous
//
#include <hip/hip_runtime.h>
#include <math.h>

#define LSEQ 2048
#define NB   32
#define DM   256
#define RT   65536   // total rows B*L
#define LDT  88      // P-transpose LDS stride: 176B row = 11x16 (b128-aligned)

// XOR slot swizzle: 8-elem block q of row c stored at slot SW8(c,q) (involution)
#define SW8(c, q) (((q) & 8) | (((q) ^ (c)) & 7))

typedef float f4 __attribute__((ext_vector_type(4)));
typedef __attribute__((ext_vector_type(4))) float f32x4;
typedef __attribute__((ext_vector_type(8))) short bf16x8;

#define MFMA16 __builtin_amdgcn_mfma_f32_16x16x32_bf16

// ---- bf16 helpers (bit-level, RNE) ----------------------------------------

__device__ __forceinline__ short f2bf(float f) {
  unsigned u = __float_as_uint(f);
  unsigned r = (u + 0x7fffu + ((u >> 16) & 1u)) >> 16;
  return (short)r;
}
__device__ __forceinline__ float bf2f(short s) {
  return __uint_as_float(((unsigned)(unsigned short)s) << 16);
}
__device__ __forceinline__ float tanh_fast(float z) {
  float e = __expf(2.f * z);
  return 1.f - __fdividef(2.f, 1.f + e);
}

// ---- x -> split bf16 + text_mean partial (fused, x read once) -------------

__global__ __launch_bounds__(256) void cvt_x_tm(const float* __restrict__ x,
                                                short* __restrict__ xh,
                                                short* __restrict__ xl,
                                                float* __restrict__ tp) {
  int lc = blockIdx.x, b = blockIdx.y, d = threadIdx.x;
  long rbase = (long)b * LSEQ + lc * 128;
  const float* xp = x + rbase * DM + d;
  short* xhp = xh + rbase * DM + d;
  short* xlp = xl + rbase * DM + d;
  float a = 0.f;
#pragma unroll 4
  for (int i = 0; i < 128; ++i) {
    float v = xp[(long)i * DM];
    a += v;
    short hh = f2bf(v);
    xhp[(long)i * DM] = hh;
    xlp[(long)i * DM] = f2bf(v - bf2f(hh));
  }
  tp[((long)lc * NB + b) * DM + d] = a;
}

__global__ __launch_bounds__(256) void tm_reduce_k(const float* __restrict__ tp,
                                                   float* __restrict__ tm) {
  int idx = blockIdx.x * 256 + threadIdx.x;   // < 8192
  int b = idx >> 8, d = idx & 255;
  float a = 0.f;
#pragma unroll
  for (int lc = 0; lc < 16; ++lc) a += tp[((long)lc * NB + b) * DM + d];
  tm[idx] = a * (1.f / LSEQ);
}

// ---- weight conversions to split-bf16 (batched over all 3 levels) ---------

__global__ __launch_bounds__(256) void cvt_ce_all(const float* __restrict__ ce0,
                                                  const float* __restrict__ ce1,
                                                  const float* __restrict__ ce2,
                                                  short* __restrict__ h,
                                                  short* __restrict__ l) {
  int hh_ = blockIdx.y;
  const float* ce = hh_ == 0 ? ce0 : (hh_ == 1 ? ce1 : ce2);
  int C = hh_ == 0 ? 21 : (hh_ == 1 ? 191 : 1009);
  int idx = blockIdx.x * 256 + threadIdx.x;   // < 131072, [c][128k]
  int c = idx >> 7, k = idx & 127;
  float v = (c < C && k < 100) ? ce[c * 100 + k] : 0.f;
  short hv = f2bf(v);
  h[hh_ * 131072 + idx] = hv;
  l[hh_ * 131072 + idx] = f2bf(v - bf2f(hv));
}

__global__ __launch_bounds__(256) void cvt_aw_all(const float* __restrict__ aw0,
                                                  const float* __restrict__ aw1,
                                                  const float* __restrict__ aw2,
                                                  short* __restrict__ h,
                                                  short* __restrict__ l) {
  int hh_ = blockIdx.y;
  const float* aw = hh_ == 0 ? aw0 : (hh_ == 1 ? aw1 : aw2);
  int idx = blockIdx.x * 256 + threadIdx.x;   // < 32768, [e][256k]
  int e = idx >> 8, k = idx & 255;
  float v = (e < 100) ? aw[k * 100 + e] : 0.f;
  short hv = f2bf(v);
  h[hh_ * 32768 + idx] = hv;
  l[hh_ * 32768 + idx] = f2bf(v - bf2f(hv));
}

// ---- s_mfma: grid 1024 linear, XCD-paired strips --------------------------
// st=(bx>>3)&1, rt=(bx&7)|((bx>>4)<<3): pair (bx, bx+8) shares the same x rows
// AND the same XCD (bx%8 equal) -> second strip's x-reads hit that XCD's L2.
// Per-wave structure identical to R10 (no register/LDS change).

__global__ __launch_bounds__(256) void s_mfma(const short* __restrict__ xh,
                                              const short* __restrict__ xl,
                                              const short* __restrict__ awh,
                                              const short* __restrict__ awl,
                                              const float* __restrict__ prevb,
                                              short* __restrict__ sGh,
                                              short* __restrict__ sGl, int hasPrev) {
  __shared__ __align__(16) short bufh[8192];   // 64 e x 128 k, swizzled slots
  __shared__ __align__(16) short bufl[8192];
  const int tid = threadIdx.x, lane = tid & 63, wv = tid >> 6;
  const int lo = lane & 15, hi = lane >> 4;
  const int bx = blockIdx.x;
  const int st = (bx >> 3) & 1;
  const int rt = (bx & 7) | ((bx >> 4) << 3);
  const long r0 = (long)rt * 128 + wv * 32;

  float pv[2][4];
#pragma unroll
  for (int m = 0; m < 2; ++m)
#pragma unroll
    for (int q = 0; q < 4; ++q)
      pv[m][q] = hasPrev ? prevb[r0 + m * 16 + hi * 4 + q] : 1.f;

  f32x4 acc[2][4];
#pragma unroll
  for (int m = 0; m < 2; ++m)
#pragma unroll
    for (int n = 0; n < 4; ++n) acc[m][n] = (f32x4){0.f, 0.f, 0.f, 0.f};

#pragma unroll 1
  for (int kh = 0; kh < 2; ++kh) {
    __syncthreads();
    {  // stage aw strip rows e=0..63 of half kh (16KB hi + 16KB lo), swizzled
      const short* gh = awh + (long)st * 64 * 256 + kh * 128;
      const short* gl = awl + (long)st * 64 * 256 + kh * 128;
#pragma unroll
      for (int j = 0; j < 4; ++j) {
        int slot = tid + j * 256;
        int c = slot >> 4, q = slot & 15;
        int dst = c * 128 + SW8(c, q) * 8;
        *(bf16x8*)(bufh + dst) = *(const bf16x8*)(gh + (long)c * 256 + q * 8);
        *(bf16x8*)(bufl + dst) = *(const bf16x8*)(gl + (long)c * 256 + q * 8);
      }
    }
    // A fragments for this k-half (global, coalesced 16B/lane)
    bf16x8 Ah[2][4], Al[2][4];
#pragma unroll
    for (int m = 0; m < 2; ++m)
#pragma unroll
      for (int ks = 0; ks < 4; ++ks) {
        long off = (r0 + m * 16 + lo) * 256 + kh * 128 + ks * 32 + hi * 8;
        Ah[m][ks] = *(const bf16x8*)(xh + off);
        Al[m][ks] = *(const bf16x8*)(xl + off);
      }
    __syncthreads();
#pragma unroll
    for (int ks = 0; ks < 4; ++ks) {
      bf16x8 Bh[4], Bl[4];
#pragma unroll
      for (int n = 0; n < 4; ++n) {
        int c = n * 16 + lo;
        int idx = c * 128 + SW8(c, ks * 4 + hi) * 8;
        Bh[n] = *(const bf16x8*)(bufh + idx);
        Bl[n] = *(const bf16x8*)(bufl + idx);
      }
#pragma unroll
      for (int n = 0; n < 4; ++n) {
        acc[0][n] = MFMA16(Ah[0][ks], Bh[n], acc[0][n], 0, 0, 0);
        acc[1][n] = MFMA16(Ah[1][ks], Bh[n], acc[1][n], 0, 0, 0);
        acc[0][n] = MFMA16(Al[0][ks], Bh[n], acc[0][n], 0, 0, 0);
        acc[1][n] = MFMA16(Al[1][ks], Bh[n], acc[1][n], 0, 0, 0);
        acc[0][n] = MFMA16(Ah[0][ks], Bl[n], acc[0][n], 0, 0, 0);
        acc[1][n] = MFMA16(Ah[1][ks], Bl[n], acc[1][n], 0, 0, 0);
      }
    }
  }

#pragma unroll
  for (int m = 0; m < 2; ++m)
#pragma unroll
    for (int n = 0; n < 4; ++n)
#pragma unroll
      for (int q = 0; q < 4; ++q) {
        long r = r0 + m * 16 + hi * 4 + q;
        int c = st * 64 + n * 16 + lo;
        float t = tanh_fast(pv[m][q] * acc[m][n][q]);
        short hh = f2bf(t);
        sGh[r * 128 + c] = hh;
        sGl[r * 128 + c] = f2bf(t - bf2f(hh));
      }
}

// ---- A-fragment load (resident) -------------------------------------------

__device__ __forceinline__ void load_afrags(const short* __restrict__ sGh,
                                            const short* __restrict__ sGl,
                                            long r0, int lo, int hi,
                                            bf16x8 (&Ah)[2][4], bf16x8 (&Al)[2][4]) {
#pragma unroll
  for (int m = 0; m < 2; ++m)
#pragma unroll
    for (int ks = 0; ks < 4; ++ks) {
      long off = (r0 + m * 16 + lo) * 128 + ks * 32 + hi * 8;
      Ah[m][ks] = *(const bf16x8*)(sGh + off);
      Al[m][ks] = *(const bf16x8*)(sGl + off);
    }
}

// ---- mfma_colP: LDS-staged ce GEMM + col partials + P=exp bf16 ------------
// grid (512, SG); transpose-LDS aliased over staging buffers (32KB total)

__global__ __launch_bounds__(256) void mfma_colP(const short* __restrict__ sGh,
                                                 const short* __restrict__ sGl,
                                                 const short* __restrict__ ceh,
                                                 const short* __restrict__ cel,
                                                 float* __restrict__ partial,
                                                 short* __restrict__ P,
                                                 int cpb, int CP) {
  __shared__ __align__(16) short smem[16384];   // bufh | bufl, tlds aliased
  short* bufh = smem;
  short* bufl = smem + 8192;
  const int tid = threadIdx.x, lane = tid & 63, wv = tid >> 6;
  const int lo = lane & 15, hi = lane >> 4;
  const long r0 = (long)blockIdx.x * 128 + wv * 32;
  const long gw = (long)blockIdx.x * 4 + wv;
  const int s0 = blockIdx.y * cpb;
  const int oct = lane & 7;
  short* tw = smem + wv * (32 * LDT);   // per-wave transpose region (aliased, 22.5KB)

  bf16x8 Ah[2][4], Al[2][4];
  load_afrags(sGh, sGl, r0, lo, hi, Ah, Al);

#pragma unroll 1
  for (int s = 0; s < cpb; ++s) {
    const int c0s = (s0 + s) * 64;
    __syncthreads();   // prior epilogue (tlds) done -> buf reusable
    {  // stage ce strip (64 cols x 128 k), hi + lo, swizzled
      const short* gh = ceh + (long)c0s * 128;
      const short* gl = cel + (long)c0s * 128;
#pragma unroll
      for (int j = 0; j < 4; ++j) {
        int slot = tid + j * 256;
        int c = slot >> 4, q = slot & 15;
        int dst = c * 128 + SW8(c, q) * 8;
        *(bf16x8*)(bufh + dst) = *(const bf16x8*)(gh + slot * 8);
        *(bf16x8*)(bufl + dst) = *(const bf16x8*)(gl + slot * 8);
      }
    }
    __syncthreads();   // buf ready

    f32x4 acc[2][4];
#pragma unroll
    for (int m = 0; m < 2; ++m)
#pragma unroll
      for (int n = 0; n < 4; ++n) acc[m][n] = (f32x4){0.f, 0.f, 0.f, 0.f};

#pragma unroll
    for (int ks = 0; ks < 4; ++ks) {
      bf16x8 Bh[4], Bl[4];
#pragma unroll
      for (int n = 0; n < 4; ++n) {
        int c = n * 16 + lo;
        int idx = c * 128 + SW8(c, ks * 4 + hi) * 8;
        Bh[n] = *(const bf16x8*)(bufh + idx);
        Bl[n] = *(const bf16x8*)(bufl + idx);
      }
#pragma unroll
      for (int n = 0; n < 4; ++n) {
        acc[0][n] = MFMA16(Ah[0][ks], Bh[n], acc[0][n], 0, 0, 0);
        acc[1][n] = MFMA16(Ah[1][ks], Bh[n], acc[1][n], 0, 0, 0);
        acc[0][n] = MFMA16(Al[0][ks], Bh[n], acc[0][n], 0, 0, 0);
        acc[1][n] = MFMA16(Al[1][ks], Bh[n], acc[1][n], 0, 0, 0);
        acc[0][n] = MFMA16(Ah[0][ks], Bl[n], acc[0][n], 0, 0, 0);
        acc[1][n] = MFMA16(Ah[1][ks], Bl[n], acc[1][n], 0, 0, 0);
      }
    }
    __syncthreads();   // all B-frag reads done -> buf dead, tlds may overwrite

    // epilogue: exp -> col partial + per-wave LDS transpose for P stores
#pragma unroll
    for (int n = 0; n < 4; ++n) {
      float sum = 0.f;
#pragma unroll
      for (int m = 0; m < 2; ++m)
#pragma unroll
        for (int q = 0; q < 4; ++q) {
          float e = __expf(acc[m][n][q]);
          sum += e;
          tw[(m * 16 + hi * 4 + q) * LDT + n * 16 + lo] = f2bf(e);
        }
      sum += __shfl_xor(sum, 16);
      sum += __shfl_xor(sum, 32);
      if (lane < 16) partial[gw * 1024 + c0s + n * 16 + lane] = sum;
    }
#pragma unroll
    for (int j = 0; j < 4; ++j) {
      int rl = (lane >> 3) + j * 8;
      bf16x8 v = *(const bf16x8*)(&tw[rl * LDT + oct * 8]);
      *(bf16x8*)(P + (r0 + rl) * (long)CP + c0s + oct * 8) = v;
    }
  }
}

// ---- wz: Z = sum of 64 wave partials per batch; w = 1/(C*Z) ---------------

__global__ __launch_bounds__(256) void wz_kernel(const float* __restrict__ partial,
                                                 float* __restrict__ Z,
                                                 float* __restrict__ w, int C) {
  int idx = blockIdx.x * 256 + threadIdx.x;  // < 32768
  int b = idx >> 10, c = idx & 1023;
  float z = 0.f;
#pragma unroll 8
  for (int i = 0; i < 64; ++i) z += partial[(long)(b * 64 + i) * 1024 + c];
  Z[idx] = z;
  w[idx] = (c < C) ? 1.f / ((float)C * z) : 0.f;
}

// ---- rowpass: out[r] = (ps[r]?) * sum_c P[r][c]*w[c]  (wave per row) ------

__global__ __launch_bounds__(256) void rowpass_k(const short* __restrict__ P,
                                                 const float* __restrict__ w,
                                                 const float* __restrict__ ps,
                                                 float* __restrict__ out, int CP) {
  const int lane = threadIdx.x & 63, wv = threadIdx.x >> 6;
  const long r = (long)blockIdx.x * 4 + wv;
  const int b = (int)(r >> 11);
  const short* Pr = P + r * (long)CP;
  const float* wb_ = w + b * 1024;
  float acc = 0.f;
  for (int c0 = lane * 8; c0 < CP; c0 += 512) {
    bf16x8 pv = *(const bf16x8*)(Pr + c0);
    f4 w0 = *(const f4*)(wb_ + c0);
    f4 w1 = *(const f4*)(wb_ + c0 + 4);
    acc = fmaf(bf2f(pv[0]), w0[0], acc);
    acc = fmaf(bf2f(pv[1]), w0[1], acc);
    acc = fmaf(bf2f(pv[2]), w0[2], acc);
    acc = fmaf(bf2f(pv[3]), w0[3], acc);
    acc = fmaf(bf2f(pv[4]), w1[0], acc);
    acc = fmaf(bf2f(pv[5]), w1[1], acc);
    acc = fmaf(bf2f(pv[6]), w1[2], acc);
    acc = fmaf(bf2f(pv[7]), w1[3], acc);
  }
  acc += __shfl_xor(acc, 1);
  acc += __shfl_xor(acc, 2);
  acc += __shfl_xor(acc, 4);
  acc += __shfl_xor(acc, 8);
  acc += __shfl_xor(acc, 16);
  acc += __shfl_xor(acc, 32);
  if (lane == 0) out[r] = ps ? acc * ps[r] : acc;
}

// ---- pooled = sum_l gs[b,l]*x[b,l,:]  (coalesced ushort2 reads) -----------

__global__ __launch_bounds__(256) void pooled_partial_k(const short* __restrict__ xh,
                                                        const float* __restrict__ gs,
                                                        float* __restrict__ pp) {
  int lc = blockIdx.x, b = blockIdx.y;
  int rr = threadIdx.x >> 7, dd = threadIdx.x & 127;
  long rbase = (long)b * LSEQ + lc * 256 + rr * 128;
  const short* xp = xh + rbase * DM + dd * 2;
  const float* gp = gs + rbase;
  float a0 = 0.f, a1 = 0.f;
#pragma unroll 4
  for (int i = 0; i < 128; ++i) {
    unsigned v = *(const unsigned*)(xp + (long)i * DM);
    float g = gp[i];
    a0 = fmaf(g, __uint_as_float((v & 0xffffu) << 16), a0);
    a1 = fmaf(g, __uint_as_float(v & 0xffff0000u), a1);
  }
  float* dst = pp + ((long)(lc * 2 + rr) * NB + b) * DM + dd * 2;
  dst[0] = a0;
  dst[1] = a1;
}

__global__ __launch_bounds__(256) void pooled_reduce_k(const float* __restrict__ pp,
                                                       float* __restrict__ pooled) {
  int idx = blockIdx.x * 256 + threadIdx.x;  // < 8192
  int b = idx >> 8, d = idx & 255;
  float a = 0.f;
#pragma unroll
  for (int lc = 0; lc < 16; ++lc) a += pp[((long)lc * NB + b) * DM + d];
  pooled[idx] = a;
}

// ---- dense = relu([tm, pooled] @ dw + db) ---------------------------------

__global__ __launch_bounds__(256) void dense_k(const float* __restrict__ tm,
                                               const float* __restrict__ pooled,
                                               const float* __restrict__ dw,
                                               const float* __restrict__ db,
                                               float* __restrict__ dense) {
  __shared__ float f[2 * DM];
  int b = blockIdx.x, t = threadIdx.x;
  f[t] = tm[b * DM + t];
  f[DM + t] = pooled[b * DM + t];
  __syncthreads();
  float a = db[t];
#pragma unroll 8
  for (int k = 0; k < 2 * DM; ++k) a = fmaf(f[k], dw[(long)k * DM + t], a);
  dense[b * DM + t] = fmaxf(a, 0.f);
}

// ---- logits = dense @ pw + pb ---------------------------------------------

__global__ __launch_bounds__(256) void logits_k(const float* __restrict__ dense,
                                                const float* __restrict__ pw,
                                                const float* __restrict__ pb,
                                                float* __restrict__ logits, int C) {
  __shared__ float dS[DM];
  int b = blockIdx.y, t = threadIdx.x;
  int c = blockIdx.x * 256 + t;
  dS[t] = dense[b * DM + t];
  __syncthreads();
  if (c < C) {
    float a = pb[c];
#pragma unroll 8
    for (int k = 0; k < DM; ++k) a = fmaf(dS[k], pw[(long)k * C + c], a);
    logits[b * 1024 + c] = a;
  }
}

// ---- softmax over C, write pred, optionally w3 = pred/(C*Z) ---------------

__global__ __launch_bounds__(256) void softmax_k(const float* __restrict__ logits,
                                                 const float* __restrict__ Z,
                                                 float* __restrict__ out,
                                                 float* __restrict__ w,
                                                 int C, int writeW) {
  __shared__ float buf[1024];
  __shared__ float red[256];
  int b = blockIdx.x, t = threadIdx.x;
  float m = -1e30f;
  for (int c = t; c < C; c += 256) {
    float v = logits[b * 1024 + c];
    buf[c] = v;
    m = fmaxf(m, v);
  }
  red[t] = m;
  __syncthreads();
  for (int s2 = 128; s2 > 0; s2 >>= 1) {
    if (t < s2) red[t] = fmaxf(red[t], red[t + s2]);
    __syncthreads();
  }
  m = red[0];
  __syncthreads();
  float sum = 0.f;
  for (int c = t; c < C; c += 256) {
    float e = __expf(buf[c] - m);
    buf[c] = e;
    sum += e;
  }
  red[t] = sum;
  __syncthreads();
  for (int s2 = 128; s2 > 0; s2 >>= 1) {
    if (t < s2) red[t] += red[t + s2];
    __syncthreads();
  }
  float inv = 1.f / red[0];
  for (int c = t; c < C; c += 256) out[(long)b * C + c] = buf[c] * inv;
  if (writeW) {
    float invC = 1.f / (float)C;
    for (int c = t; c < 1024; c += 256)
      w[b * 1024 + c] = (c < C) ? (buf[c] * inv) * invC / Z[b * 1024 + c] : 0.f;
  }
}

// ---- host -----------------------------------------------------------------

extern "C" void kernel_launch(void* const* d_in, const int* in_sizes, int n_in,
                              void* d_out, int out_size, void* d_ws, size_t ws_size,
                              hipStream_t stream) {
  (void)in_sizes; (void)n_in; (void)out_size; (void)ws_size;
  const float* x = (const float*)d_in[0];

  const int Cs[3]     = {21, 191, 1009};
  const int CPs[3]    = {64, 192, 1024};  // padded P row length
  const int SGs[3]    = {1, 1, 2};        // strip-groups (grid.y)
  const int CPBs[3]   = {1, 3, 8};        // strips per block; SG*CPB*64 == CP
  const int outoff[3] = {0, 672, 6784};

  char* base = (char*)d_ws;
  short* xh  = (short*)base; base += (size_t)RT * 256 * 2;
  short* xl  = (short*)base; base += (size_t)RT * 256 * 2;
  short* sGh = (short*)base; base += (size_t)RT * 128 * 2;
  short* sGl = (short*)base; base += (size_t)RT * 128 * 2;
  short* Pb  = (short*)base; base += (size_t)RT * 1024 * 2;   // P bf16
  short* ceh = (short*)base; base += (size_t)3 * 131072 * 2;
  short* cel = (short*)base; base += (size_t)3 * 131072 * 2;
  short* awh = (short*)base; base += (size_t)3 * 32768 * 2;
  short* awl = (short*)base; base += (size_t)3 * 32768 * 2;
  float* partial = (float*)base; base += (size_t)2048 * 1024 * 4;
  float* Zb     = (float*)base; base += 32768 * 4;
  float* wb     = (float*)base; base += 32768 * 4;
  float* gs     = (float*)base; base += RT * 4;
  float* prevb  = (float*)base; base += RT * 4;
  float* tp     = (float*)base; base += 131072 * 4;
  float* tm     = (float*)base; base += 8192 * 4;
  float* pp     = (float*)base; base += 131072 * 4;
  float* pooled = (float*)base; base += 8192 * 4;
  float* dense  = (float*)base; base += 8192 * 4;
  float* logits = (float*)base; base += 32768 * 4;

  cvt_x_tm<<<dim3(16, NB), 256, 0, stream>>>(x, xh, xl, tp);
  tm_reduce_k<<<32, 256, 0, stream>>>(tp, tm);
  cvt_ce_all<<<dim3(512, 3), 256, 0, stream>>>((const float*)d_in[1],
                                               (const float*)d_in[7],
                                               (const float*)d_in[13], ceh, cel);
  cvt_aw_all<<<dim3(128, 3), 256, 0, stream>>>((const float*)d_in[2],
                                               (const float*)d_in[8],
                                               (const float*)d_in[14], awh, awl);

  for (int h = 0; h < 3; ++h) {
    const float* dw = (const float*)d_in[1 + 6 * h + 2];
    const float* db = (const float*)d_in[1 + 6 * h + 3];
    const float* pw = (const float*)d_in[1 + 6 * h + 4];
    const float* pb = (const float*)d_in[1 + 6 * h + 5];
    const short* ch = ceh + h * 131072;
    const short* cl = cel + h * 131072;
    const int C = Cs[h], CP = CPs[h], SG = SGs[h], CPB = CPBs[h];

    s_mfma<<<1024, 256, 0, stream>>>(xh, xl, awh + h * 32768, awl + h * 32768,
                                     prevb, sGh, sGl, h > 0 ? 1 : 0);
    mfma_colP<<<dim3(512, SG), 256, 0, stream>>>(sGh, sGl, ch, cl, partial, Pb, CPB, CP);
    wz_kernel<<<128, 256, 0, stream>>>(partial, Zb, wb, C);
    rowpass_k<<<RT / 4, 256, 0, stream>>>(Pb, wb, h > 0 ? prevb : nullptr, gs, CP);
    pooled_partial_k<<<dim3(8, NB), 256, 0, stream>>>(xh, gs, pp);
    pooled_reduce_k<<<32, 256, 0, stream>>>(pp, pooled);
    dense_k<<<NB, 256, 0, stream>>>(tm, pooled, dw, db, dense);
    logits_k<<<dim3((C + 255) / 256, NB), 256, 0, stream>>>(dense, pw, pb, logits, C);
    softmax_k<<<NB, 256, 0, stream>>>(logits, Zb, (float*)d_out + outoff[h], wb, C,
                                      h < 2 ? 1 : 0);
    if (h < 2)
      rowpass_k<<<RT / 4, 256, 0, stream>>>(Pb, wb, nullptr, prevb, CP);
  }
}

// Round 17
// 493.100 us; speedup vs baseline: 1.3288x; 1.0093x over previous
//
#include <hip/hip_runtime.h>
#include <hip/hip_bf16.h>
#include <math.h>

#define LSEQ 2048
#define NB   32
#define DM   256
#define RT   65536   // total rows B*L
#define LDT  88      // P-transpose LDS stride: 176B row = 11x16 (b128-aligned)

// XOR slot swizzle: 8-elem block q of row c stored at slot SW8(c,q) (involution)
#define SW8(c, q) (((q) & 8) | (((q) ^ (c)) & 7))

typedef float f4 __attribute__((ext_vector_type(4)));
typedef __attribute__((ext_vector_type(4))) float f32x4;
typedef __attribute__((ext_vector_type(8))) short bf16x8;

#define MFMA16 __builtin_amdgcn_mfma_f32_16x16x32_bf16

// ---- bf16 helpers: HW conversion (compiler emits v_cvt_pk_bf16_f32) -------

__device__ __forceinline__ short f2bf(float f) {
  union { __hip_bfloat16 b; short s; } u;
  u.b = __float2bfloat16(f);
  return u.s;
}
__device__ __forceinline__ float bf2f(short s) {
  return __uint_as_float(((unsigned)(unsigned short)s) << 16);
}
__device__ __forceinline__ float tanh_fast(float z) {
  float e = __expf(2.f * z);
  return 1.f - __fdividef(2.f, 1.f + e);
}

// ---- x -> split bf16 + text_mean partial (fused, x read once) -------------

__global__ __launch_bounds__(256) void cvt_x_tm(const float* __restrict__ x,
                                                short* __restrict__ xh,
                                                short* __restrict__ xl,
                                                float* __restrict__ tp) {
  int lc = blockIdx.x, b = blockIdx.y, d = threadIdx.x;
  long rbase = (long)b * LSEQ + lc * 128;
  const float* xp = x + rbase * DM + d;
  short* xhp = xh + rbase * DM + d;
  short* xlp = xl + rbase * DM + d;
  float a = 0.f;
#pragma unroll 4
  for (int i = 0; i < 128; ++i) {
    float v = xp[(long)i * DM];
    a += v;
    short hh = f2bf(v);
    xhp[(long)i * DM] = hh;
    xlp[(long)i * DM] = f2bf(v - bf2f(hh));
  }
  tp[((long)lc * NB + b) * DM + d] = a;
}

__global__ __launch_bounds__(256) void tm_reduce_k(const float* __restrict__ tp,
                                                   float* __restrict__ tm) {
  int idx = blockIdx.x * 256 + threadIdx.x;   // < 8192
  int b = idx >> 8, d = idx & 255;
  float a = 0.f;
#pragma unroll
  for (int lc = 0; lc < 16; ++lc) a += tp[((long)lc * NB + b) * DM + d];
  tm[idx] = a * (1.f / LSEQ);
}

// ---- weight conversions to split-bf16 (batched over all 3 levels) ---------

__global__ __launch_bounds__(256) void cvt_ce_all(const float* __restrict__ ce0,
                                                  const float* __restrict__ ce1,
                                                  const float* __restrict__ ce2,
                                                  short* __restrict__ h,
                                                  short* __restrict__ l) {
  int hh_ = blockIdx.y;
  const float* ce = hh_ == 0 ? ce0 : (hh_ == 1 ? ce1 : ce2);
  int C = hh_ == 0 ? 21 : (hh_ == 1 ? 191 : 1009);
  int idx = blockIdx.x * 256 + threadIdx.x;   // < 131072, [c][128k]
  int c = idx >> 7, k = idx & 127;
  float v = (c < C && k < 100) ? ce[c * 100 + k] : 0.f;
  short hv = f2bf(v);
  h[hh_ * 131072 + idx] = hv;
  l[hh_ * 131072 + idx] = f2bf(v - bf2f(hv));
}

__global__ __launch_bounds__(256) void cvt_aw_all(const float* __restrict__ aw0,
                                                  const float* __restrict__ aw1,
                                                  const float* __restrict__ aw2,
                                                  short* __restrict__ h,
                                                  short* __restrict__ l) {
  int hh_ = blockIdx.y;
  const float* aw = hh_ == 0 ? aw0 : (hh_ == 1 ? aw1 : aw2);
  int idx = blockIdx.x * 256 + threadIdx.x;   // < 32768, [e][256k]
  int e = idx >> 8, k = idx & 255;
  float v = (e < 100) ? aw[k * 100 + e] : 0.f;
  short hv = f2bf(v);
  h[hh_ * 32768 + idx] = hv;
  l[hh_ * 32768 + idx] = f2bf(v - bf2f(hv));
}

// ---- s_mfma: grid 1024 linear, XCD-paired strips --------------------------
// st=(bx>>3)&1, rt=(bx&7)|((bx>>4)<<3): pair (bx, bx+8) shares the same x rows
// AND the same XCD (bx%8 equal) -> second strip's x-reads hit that XCD's L2.

__global__ __launch_bounds__(256) void s_mfma(const short* __restrict__ xh,
                                              const short* __restrict__ xl,
                                              const short* __restrict__ awh,
                                              const short* __restrict__ awl,
                                              const float* __restrict__ prevb,
                                              short* __restrict__ sGh,
                                              short* __restrict__ sGl, int hasPrev) {
  __shared__ __align__(16) short bufh[8192];   // 64 e x 128 k, swizzled slots
  __shared__ __align__(16) short bufl[8192];
  const int tid = threadIdx.x, lane = tid & 63, wv = tid >> 6;
  const int lo = lane & 15, hi = lane >> 4;
  const int bx = blockIdx.x;
  const int st = (bx >> 3) & 1;
  const int rt = (bx & 7) | ((bx >> 4) << 3);
  const long r0 = (long)rt * 128 + wv * 32;

  float pv[2][4];
#pragma unroll
  for (int m = 0; m < 2; ++m)
#pragma unroll
    for (int q = 0; q < 4; ++q)
      pv[m][q] = hasPrev ? prevb[r0 + m * 16 + hi * 4 + q] : 1.f;

  f32x4 acc[2][4];
#pragma unroll
  for (int m = 0; m < 2; ++m)
#pragma unroll
    for (int n = 0; n < 4; ++n) acc[m][n] = (f32x4){0.f, 0.f, 0.f, 0.f};

#pragma unroll 1
  for (int kh = 0; kh < 2; ++kh) {
    __syncthreads();
    {  // stage aw strip rows e=0..63 of half kh (16KB hi + 16KB lo), swizzled
      const short* gh = awh + (long)st * 64 * 256 + kh * 128;
      const short* gl = awl + (long)st * 64 * 256 + kh * 128;
#pragma unroll
      for (int j = 0; j < 4; ++j) {
        int slot = tid + j * 256;
        int c = slot >> 4, q = slot & 15;
        int dst = c * 128 + SW8(c, q) * 8;
        *(bf16x8*)(bufh + dst) = *(const bf16x8*)(gh + (long)c * 256 + q * 8);
        *(bf16x8*)(bufl + dst) = *(const bf16x8*)(gl + (long)c * 256 + q * 8);
      }
    }
    // A fragments for this k-half (global, coalesced 16B/lane)
    bf16x8 Ah[2][4], Al[2][4];
#pragma unroll
    for (int m = 0; m < 2; ++m)
#pragma unroll
      for (int ks = 0; ks < 4; ++ks) {
        long off = (r0 + m * 16 + lo) * 256 + kh * 128 + ks * 32 + hi * 8;
        Ah[m][ks] = *(const bf16x8*)(xh + off);
        Al[m][ks] = *(const bf16x8*)(xl + off);
      }
    __syncthreads();
#pragma unroll
    for (int ks = 0; ks < 4; ++ks) {
      bf16x8 Bh[4], Bl[4];
#pragma unroll
      for (int n = 0; n < 4; ++n) {
        int c = n * 16 + lo;
        int idx = c * 128 + SW8(c, ks * 4 + hi) * 8;
        Bh[n] = *(const bf16x8*)(bufh + idx);
        Bl[n] = *(const bf16x8*)(bufl + idx);
      }
#pragma unroll
      for (int n = 0; n < 4; ++n) {
        acc[0][n] = MFMA16(Ah[0][ks], Bh[n], acc[0][n], 0, 0, 0);
        acc[1][n] = MFMA16(Ah[1][ks], Bh[n], acc[1][n], 0, 0, 0);
        acc[0][n] = MFMA16(Al[0][ks], Bh[n], acc[0][n], 0, 0, 0);
        acc[1][n] = MFMA16(Al[1][ks], Bh[n], acc[1][n], 0, 0, 0);
        acc[0][n] = MFMA16(Ah[0][ks], Bl[n], acc[0][n], 0, 0, 0);
        acc[1][n] = MFMA16(Ah[1][ks], Bl[n], acc[1][n], 0, 0, 0);
      }
    }
  }

#pragma unroll
  for (int m = 0; m < 2; ++m)
#pragma unroll
    for (int n = 0; n < 4; ++n)
#pragma unroll
      for (int q = 0; q < 4; ++q) {
        long r = r0 + m * 16 + hi * 4 + q;
        int c = st * 64 + n * 16 + lo;
        float t = tanh_fast(pv[m][q] * acc[m][n][q]);
        short hh = f2bf(t);
        sGh[r * 128 + c] = hh;
        sGl[r * 128 + c] = f2bf(t - bf2f(hh));
      }
}

// ---- A-fragment load (resident) -------------------------------------------

__device__ __forceinline__ void load_afrags(const short* __restrict__ sGh,
                                            const short* __restrict__ sGl,
                                            long r0, int lo, int hi,
                                            bf16x8 (&Ah)[2][4], bf16x8 (&Al)[2][4]) {
#pragma unroll
  for (int m = 0; m < 2; ++m)
#pragma unroll
    for (int ks = 0; ks < 4; ++ks) {
      long off = (r0 + m * 16 + lo) * 128 + ks * 32 + hi * 8;
      Ah[m][ks] = *(const bf16x8*)(sGh + off);
      Al[m][ks] = *(const bf16x8*)(sGl + off);
    }
}

// ---- mfma_colP: LDS-staged ce GEMM + col partials + P=exp bf16 ------------
// grid (512, SG); transpose-LDS aliased over staging buffers (32KB total)

__global__ __launch_bounds__(256) void mfma_colP(const short* __restrict__ sGh,
                                                 const short* __restrict__ sGl,
                                                 const short* __restrict__ ceh,
                                                 const short* __restrict__ cel,
                                                 float* __restrict__ partial,
                                                 short* __restrict__ P,
                                                 int cpb, int CP) {
  __shared__ __align__(16) short smem[16384];   // bufh | bufl, tlds aliased
  short* bufh = smem;
  short* bufl = smem + 8192;
  const int tid = threadIdx.x, lane = tid & 63, wv = tid >> 6;
  const int lo = lane & 15, hi = lane >> 4;
  const long r0 = (long)blockIdx.x * 128 + wv * 32;
  const long gw = (long)blockIdx.x * 4 + wv;
  const int s0 = blockIdx.y * cpb;
  const int oct = lane & 7;
  short* tw = smem + wv * (32 * LDT);   // per-wave transpose region (aliased, 22.5KB)

  bf16x8 Ah[2][4], Al[2][4];
  load_afrags(sGh, sGl, r0, lo, hi, Ah, Al);

#pragma unroll 1
  for (int s = 0; s < cpb; ++s) {
    const int c0s = (s0 + s) * 64;
    __syncthreads();   // prior epilogue (tlds) done -> buf reusable
    {  // stage ce strip (64 cols x 128 k), hi + lo, swizzled
      const short* gh = ceh + (long)c0s * 128;
      const short* gl = cel + (long)c0s * 128;
#pragma unroll
      for (int j = 0; j < 4; ++j) {
        int slot = tid + j * 256;
        int c = slot >> 4, q = slot & 15;
        int dst = c * 128 + SW8(c, q) * 8;
        *(bf16x8*)(bufh + dst) = *(const bf16x8*)(gh + slot * 8);
        *(bf16x8*)(bufl + dst) = *(const bf16x8*)(gl + slot * 8);
      }
    }
    __syncthreads();   // buf ready

    f32x4 acc[2][4];
#pragma unroll
    for (int m = 0; m < 2; ++m)
#pragma unroll
      for (int n = 0; n < 4; ++n) acc[m][n] = (f32x4){0.f, 0.f, 0.f, 0.f};

#pragma unroll
    for (int ks = 0; ks < 4; ++ks) {
      bf16x8 Bh[4], Bl[4];
#pragma unroll
      for (int n = 0; n < 4; ++n) {
        int c = n * 16 + lo;
        int idx = c * 128 + SW8(c, ks * 4 + hi) * 8;
        Bh[n] = *(const bf16x8*)(bufh + idx);
        Bl[n] = *(const bf16x8*)(bufl + idx);
      }
#pragma unroll
      for (int n = 0; n < 4; ++n) {
        acc[0][n] = MFMA16(Ah[0][ks], Bh[n], acc[0][n], 0, 0, 0);
        acc[1][n] = MFMA16(Ah[1][ks], Bh[n], acc[1][n], 0, 0, 0);
        acc[0][n] = MFMA16(Al[0][ks], Bh[n], acc[0][n], 0, 0, 0);
        acc[1][n] = MFMA16(Al[1][ks], Bh[n], acc[1][n], 0, 0, 0);
        acc[0][n] = MFMA16(Ah[0][ks], Bl[n], acc[0][n], 0, 0, 0);
        acc[1][n] = MFMA16(Ah[1][ks], Bl[n], acc[1][n], 0, 0, 0);
      }
    }
    __syncthreads();   // all B-frag reads done -> buf dead, tlds may overwrite

    // epilogue: exp -> col partial + per-wave LDS transpose for P stores
#pragma unroll
    for (int n = 0; n < 4; ++n) {
      float sum = 0.f;
#pragma unroll
      for (int m = 0; m < 2; ++m)
#pragma unroll
        for (int q = 0; q < 4; ++q) {
          float e = __expf(acc[m][n][q]);
          sum += e;
          tw[(m * 16 + hi * 4 + q) * LDT + n * 16 + lo] = f2bf(e);
        }
      sum += __shfl_xor(sum, 16);
      sum += __shfl_xor(sum, 32);
      if (lane < 16) partial[gw * 1024 + c0s + n * 16 + lane] = sum;
    }
#pragma unroll
    for (int j = 0; j < 4; ++j) {
      int rl = (lane >> 3) + j * 8;
      bf16x8 v = *(const bf16x8*)(&tw[rl * LDT + oct * 8]);
      *(bf16x8*)(P + (r0 + rl) * (long)CP + c0s + oct * 8) = v;
    }
  }
}

// ---- wz: Z = sum of 64 wave partials per batch; w = 1/(C*Z) ---------------

__global__ __launch_bounds__(256) void wz_kernel(const float* __restrict__ partial,
                                                 float* __restrict__ Z,
                                                 float* __restrict__ w, int C) {
  int idx = blockIdx.x * 256 + threadIdx.x;  // < 32768
  int b = idx >> 10, c = idx & 1023;
  float z = 0.f;
#pragma unroll 8
  for (int i = 0; i < 64; ++i) z += partial[(long)(b * 64 + i) * 1024 + c];
  Z[idx] = z;
  w[idx] = (c < C) ? 1.f / ((float)C * z) : 0.f;
}

// ---- rowpass: out[r] = (ps[r]?) * sum_c P[r][c]*w[c]  (wave per row) ------

__global__ __launch_bounds__(256) void rowpass_k(const short* __restrict__ P,
                                                 const float* __restrict__ w,
                                                 const float* __restrict__ ps,
                                                 float* __restrict__ out, int CP) {
  const int lane = threadIdx.x & 63, wv = threadIdx.x >> 6;
  const long r = (long)blockIdx.x * 4 + wv;
  const int b = (int)(r >> 11);
  const short* Pr = P + r * (long)CP;
  const float* wb_ = w + b * 1024;
  float acc = 0.f;
  for (int c0 = lane * 8; c0 < CP; c0 += 512) {
    bf16x8 pv = *(const bf16x8*)(Pr + c0);
    f4 w0 = *(const f4*)(wb_ + c0);
    f4 w1 = *(const f4*)(wb_ + c0 + 4);
    acc = fmaf(bf2f(pv[0]), w0[0], acc);
    acc = fmaf(bf2f(pv[1]), w0[1], acc);
    acc = fmaf(bf2f(pv[2]), w0[2], acc);
    acc = fmaf(bf2f(pv[3]), w0[3], acc);
    acc = fmaf(bf2f(pv[4]), w1[0], acc);
    acc = fmaf(bf2f(pv[5]), w1[1], acc);
    acc = fmaf(bf2f(pv[6]), w1[2], acc);
    acc = fmaf(bf2f(pv[7]), w1[3], acc);
  }
  acc += __shfl_xor(acc, 1);
  acc += __shfl_xor(acc, 2);
  acc += __shfl_xor(acc, 4);
  acc += __shfl_xor(acc, 8);
  acc += __shfl_xor(acc, 16);
  acc += __shfl_xor(acc, 32);
  if (lane == 0) out[r] = ps ? acc * ps[r] : acc;
}

// ---- pooled = sum_l gs[b,l]*x[b,l,:]  (coalesced ushort2 reads) -----------

__global__ __launch_bounds__(256) void pooled_partial_k(const short* __restrict__ xh,
                                                        const float* __restrict__ gs,
                                                        float* __restrict__ pp) {
  int lc = blockIdx.x, b = blockIdx.y;
  int rr = threadIdx.x >> 7, dd = threadIdx.x & 127;
  long rbase = (long)b * LSEQ + lc * 256 + rr * 128;
  const short* xp = xh + rbase * DM + dd * 2;
  const float* gp = gs + rbase;
  float a0 = 0.f, a1 = 0.f;
#pragma unroll 4
  for (int i = 0; i < 128; ++i) {
    unsigned v = *(const unsigned*)(xp + (long)i * DM);
    float g = gp[i];
    a0 = fmaf(g, __uint_as_float((v & 0xffffu) << 16), a0);
    a1 = fmaf(g, __uint_as_float(v & 0xffff0000u), a1);
  }
  float* dst = pp + ((long)(lc * 2 + rr) * NB + b) * DM + dd * 2;
  dst[0] = a0;
  dst[1] = a1;
}

__global__ __launch_bounds__(256) void pooled_reduce_k(const float* __restrict__ pp,
                                                       float* __restrict__ pooled) {
  int idx = blockIdx.x * 256 + threadIdx.x;  // < 8192
  int b = idx >> 8, d = idx & 255;
  float a = 0.f;
#pragma unroll
  for (int lc = 0; lc < 16; ++lc) a += pp[((long)lc * NB + b) * DM + d];
  pooled[idx] = a;
}

// ---- dense = relu([tm, pooled] @ dw + db) ---------------------------------

__global__ __launch_bounds__(256) void dense_k(const float* __restrict__ tm,
                                               const float* __restrict__ pooled,
                                               const float* __restrict__ dw,
                                               const float* __restrict__ db,
                                               float* __restrict__ dense) {
  __shared__ float f[2 * DM];
  int b = blockIdx.x, t = threadIdx.x;
  f[t] = tm[b * DM + t];
  f[DM + t] = pooled[b * DM + t];
  __syncthreads();
  float a = db[t];
#pragma unroll 8
  for (int k = 0; k < 2 * DM; ++k) a = fmaf(f[k], dw[(long)k * DM + t], a);
  dense[b * DM + t] = fmaxf(a, 0.f);
}

// ---- logits = dense @ pw + pb ---------------------------------------------

__global__ __launch_bounds__(256) void logits_k(const float* __restrict__ dense,
                                                const float* __restrict__ pw,
                                                const float* __restrict__ pb,
                                                float* __restrict__ logits, int C) {
  __shared__ float dS[DM];
  int b = blockIdx.y, t = threadIdx.x;
  int c = blockIdx.x * 256 + t;
  dS[t] = dense[b * DM + t];
  __syncthreads();
  if (c < C) {
    float a = pb[c];
#pragma unroll 8
    for (int k = 0; k < DM; ++k) a = fmaf(dS[k], pw[(long)k * C + c], a);
    logits[b * 1024 + c] = a;
  }
}

// ---- softmax over C, write pred, optionally w3 = pred/(C*Z) ---------------

__global__ __launch_bounds__(256) void softmax_k(const float* __restrict__ logits,
                                                 const float* __restrict__ Z,
                                                 float* __restrict__ out,
                                                 float* __restrict__ w,
                                                 int C, int writeW) {
  __shared__ float buf[1024];
  __shared__ float red[256];
  int b = blockIdx.x, t = threadIdx.x;
  float m = -1e30f;
  for (int c = t; c < C; c += 256) {
    float v = logits[b * 1024 + c];
    buf[c] = v;
    m = fmaxf(m, v);
  }
  red[t] = m;
  __syncthreads();
  for (int s2 = 128; s2 > 0; s2 >>= 1) {
    if (t < s2) red[t] = fmaxf(red[t], red[t + s2]);
    __syncthreads();
  }
  m = red[0];
  __syncthreads();
  float sum = 0.f;
  for (int c = t; c < C; c += 256) {
    float e = __expf(buf[c] - m);
    buf[c] = e;
    sum += e;
  }
  red[t] = sum;
  __syncthreads();
  for (int s2 = 128; s2 > 0; s2 >>= 1) {
    if (t < s2) red[t] += red[t + s2];
    __syncthreads();
  }
  float inv = 1.f / red[0];
  for (int c = t; c < C; c += 256) out[(long)b * C + c] = buf[c] * inv;
  if (writeW) {
    float invC = 1.f / (float)C;
    for (int c = t; c < 1024; c += 256)
      w[b * 1024 + c] = (c < C) ? (buf[c] * inv) * invC / Z[b * 1024 + c] : 0.f;
  }
}

// ---- host -----------------------------------------------------------------

extern "C" void kernel_launch(void* const* d_in, const int* in_sizes, int n_in,
                              void* d_out, int out_size, void* d_ws, size_t ws_size,
                              hipStream_t stream) {
  (void)in_sizes; (void)n_in; (void)out_size; (void)ws_size;
  const float* x = (const float*)d_in[0];

  const int Cs[3]     = {21, 191, 1009};
  const int CPs[3]    = {64, 192, 1024};  // padded P row length
  const int SGs[3]    = {1, 1, 2};        // strip-groups (grid.y)
  const int CPBs[3]   = {1, 3, 8};        // strips per block; SG*CPB*64 == CP
  const int outoff[3] = {0, 672, 6784};

  char* base = (char*)d_ws;
  short* xh  = (short*)base; base += (size_t)RT * 256 * 2;
  short* xl  = (short*)base; base += (size_t)RT * 256 * 2;
  short* sGh = (short*)base; base += (size_t)RT * 128 * 2;
  short* sGl = (short*)base; base += (size_t)RT * 128 * 2;
  short* Pb  = (short*)base; base += (size_t)RT * 1024 * 2;   // P bf16
  short* ceh = (short*)base; base += (size_t)3 * 131072 * 2;
  short* cel = (short*)base; base += (size_t)3 * 131072 * 2;
  short* awh = (short*)base; base += (size_t)3 * 32768 * 2;
  short* awl = (short*)base; base += (size_t)3 * 32768 * 2;
  float* partial = (float*)base; base += (size_t)2048 * 1024 * 4;
  float* Zb     = (float*)base; base += 32768 * 4;
  float* wb     = (float*)base; base += 32768 * 4;
  float* gs     = (float*)base; base += RT * 4;
  float* prevb  = (float*)base; base += RT * 4;
  float* tp     = (float*)base; base += 131072 * 4;
  float* tm     = (float*)base; base += 8192 * 4;
  float* pp     = (float*)base; base += 131072 * 4;
  float* pooled = (float*)base; base += 8192 * 4;
  float* dense  = (float*)base; base += 8192 * 4;
  float* logits = (float*)base; base += 32768 * 4;

  cvt_x_tm<<<dim3(16, NB), 256, 0, stream>>>(x, xh, xl, tp);
  tm_reduce_k<<<32, 256, 0, stream>>>(tp, tm);
  cvt_ce_all<<<dim3(512, 3), 256, 0, stream>>>((const float*)d_in[1],
                                               (const float*)d_in[7],
                                               (const float*)d_in[13], ceh, cel);
  cvt_aw_all<<<dim3(128, 3), 256, 0, stream>>>((const float*)d_in[2],
                                               (const float*)d_in[8],
                                               (const float*)d_in[14], awh, awl);

  for (int h = 0; h < 3; ++h) {
    const float* dw = (const float*)d_in[1 + 6 * h + 2];
    const float* db = (const float*)d_in[1 + 6 * h + 3];
    const float* pw = (const float*)d_in[1 + 6 * h + 4];
    const float* pb = (const float*)d_in[1 + 6 * h + 5];
    const short* ch = ceh + h * 131072;
    const short* cl = cel + h * 131072;
    const int C = Cs[h], CP = CPs[h], SG = SGs[h], CPB = CPBs[h];

    s_mfma<<<1024, 256, 0, stream>>>(xh, xl, awh + h * 32768, awl + h * 32768,
                                     prevb, sGh, sGl, h > 0 ? 1 : 0);
    mfma_colP<<<dim3(512, SG), 256, 0, stream>>>(sGh, sGl, ch, cl, partial, Pb, CPB, CP);
    wz_kernel<<<128, 256, 0, stream>>>(partial, Zb, wb, C);
    rowpass_k<<<RT / 4, 256, 0, stream>>>(Pb, wb, h > 0 ? prevb : nullptr, gs, CP);
    pooled_partial_k<<<dim3(8, NB), 256, 0, stream>>>(xh, gs, pp);
    pooled_reduce_k<<<32, 256, 0, stream>>>(pp, pooled);
    dense_k<<<NB, 256, 0, stream>>>(tm, pooled, dw, db, dense);
    logits_k<<<dim3((C + 255) / 256, NB), 256, 0, stream>>>(dense, pw, pb, logits, C);
    softmax_k<<<NB, 256, 0, stream>>>(logits, Zb, (float*)d_out + outoff[h], wb, C,
                                      h < 2 ? 1 : 0);
    if (h < 2)
      rowpass_k<<<RT / 4, 256, 0, stream>>>(Pb, wb, nullptr, prevb, CP);
  }
}